// Round 1
// baseline (12539.974 us; speedup 1.0000x reference)
//
#include <hip/hip_runtime.h>
#include <math.h>

static __device__ __forceinline__ float elu_f(float x) {
    return x > 0.0f ? x : expm1f(x);
}

__global__ void k_deg(const int* __restrict__ dst, const float* __restrict__ w,
                      float* __restrict__ deg, int E) {
    int i = blockIdx.x * blockDim.x + threadIdx.x;
    int stride = gridDim.x * blockDim.x;
    for (; i < E; i += stride) atomicAdd(&deg[dst[i]], w[i]);
}

__global__ void k_dinv(float* __restrict__ deg, int N) {
    int i = blockIdx.x * blockDim.x + threadIdx.x;
    int stride = gridDim.x * blockDim.x;
    for (; i < N; i += stride) deg[i] = rsqrtf(deg[i] + 1.0f);
}

// y[i,:] = x[i,:] @ W (+ bias if provided). One thread per node, W in LDS.
template<int IN, int OUT>
__global__ void k_xw(const float* __restrict__ x, const float* __restrict__ W,
                     float* __restrict__ y, int N, const float* __restrict__ bias) {
    __shared__ float sW[IN * OUT];
    __shared__ float sb[OUT];
    for (int t = threadIdx.x; t < IN * OUT; t += blockDim.x) sW[t] = W[t];
    if (threadIdx.x < OUT) sb[threadIdx.x] = bias ? bias[threadIdx.x] : 0.0f;
    __syncthreads();
    int i = blockIdx.x * blockDim.x + threadIdx.x;
    int stride = gridDim.x * blockDim.x;
    for (; i < N; i += stride) {
        const float* xr = x + (size_t)i * IN;
        float acc[OUT];
        #pragma unroll
        for (int o = 0; o < OUT; o++) acc[o] = sb[o];
        #pragma unroll
        for (int k = 0; k < IN; k++) {
            float xv = xr[k];
            #pragma unroll
            for (int o = 0; o < OUT; o++) acc[o] += xv * sW[k * OUT + o];
        }
        float* yr = y + (size_t)i * OUT;
        #pragma unroll
        for (int o = 0; o < OUT; o++) yr[o] = acc[o];
    }
}

// agg[dst,:] += coef * xw[src,:] for each edge; coef = dinv[s]*w*dinv[d]
template<int F>
__global__ void k_edge(const int* __restrict__ src, const int* __restrict__ dst,
                       const float* __restrict__ w, const float* __restrict__ dinv,
                       const float* __restrict__ xw, float* __restrict__ agg, int E) {
    int e = blockIdx.x * blockDim.x + threadIdx.x;
    int stride = gridDim.x * blockDim.x;
    for (; e < E; e += stride) {
        int s = src[e], d = dst[e];
        float c = dinv[s] * w[e] * dinv[d];
        const float4* xs = (const float4*)(xw + (size_t)s * F);
        float* ad = agg + (size_t)d * F;
        #pragma unroll
        for (int f = 0; f < F / 4; f++) {
            float4 v = xs[f];
            atomicAdd(&ad[4 * f + 0], v.x * c);
            atomicAdd(&ad[4 * f + 1], v.y * c);
            atomicAdd(&ad[4 * f + 2], v.z * c);
            atomicAdd(&ad[4 * f + 3], v.w * c);
        }
    }
}

// h = elu(agg + xw * dinv^2 + b), in place into agg
template<int F>
__global__ void k_combine(float* __restrict__ agg, const float* __restrict__ xw,
                          const float* __restrict__ dinv, const float* __restrict__ b,
                          int N) {
    int idx = blockIdx.x * blockDim.x + threadIdx.x;
    int stride = gridDim.x * blockDim.x;
    int total = N * F;
    for (; idx < total; idx += stride) {
        int i = idx / F, f = idx & (F - 1);
        float di = dinv[i];
        float v = agg[idx] + xw[idx] * di * di + b[f];
        agg[idx] = elu_f(v);
    }
}

// bipartite: agg[dst,:] += m[src,:]
__global__ void k_bi(const int* __restrict__ src, const int* __restrict__ dst,
                     const float* __restrict__ m, float* __restrict__ agg, int E) {
    int e = blockIdx.x * blockDim.x + threadIdx.x;
    int stride = gridDim.x * blockDim.x;
    for (; e < E; e += stride) {
        int s = src[e], d = dst[e];
        const float4* ms = (const float4*)(m + (size_t)s * 32);
        float* ad = agg + (size_t)d * 32;
        #pragma unroll
        for (int f = 0; f < 8; f++) {
            float4 v = ms[f];
            atomicAdd(&ad[4 * f + 0], v.x);
            atomicAdd(&ad[4 * f + 1], v.y);
            atomicAdd(&ad[4 * f + 2], v.z);
            atomicAdd(&ad[4 * f + 3], v.w);
        }
    }
}

// out[i,:] = elu(agg[i,:]) @ mlp_w + mlp_b
__global__ void k_out(const float* __restrict__ agg, const float* __restrict__ W,
                      const float* __restrict__ b, float* __restrict__ out, int N) {
    __shared__ float sW[32 * 10];
    __shared__ float sb[10];
    for (int t = threadIdx.x; t < 320; t += blockDim.x) sW[t] = W[t];
    if (threadIdx.x < 10) sb[threadIdx.x] = b[threadIdx.x];
    __syncthreads();
    int i = blockIdx.x * blockDim.x + threadIdx.x;
    int stride = gridDim.x * blockDim.x;
    for (; i < N; i += stride) {
        const float* ar = agg + (size_t)i * 32;
        float acc[10];
        #pragma unroll
        for (int c = 0; c < 10; c++) acc[c] = sb[c];
        #pragma unroll
        for (int k = 0; k < 32; k++) {
            float a = elu_f(ar[k]);
            #pragma unroll
            for (int c = 0; c < 10; c++) acc[c] += a * sW[k * 10 + c];
        }
        float* orow = out + (size_t)i * 10;
        #pragma unroll
        for (int c = 0; c < 10; c++) orow[c] = acc[c];
    }
}

extern "C" void kernel_launch(void* const* d_in, const int* in_sizes, int n_in,
                              void* d_out, int out_size, void* d_ws, size_t ws_size,
                              hipStream_t stream) {
    const float* x_ho   = (const float*)d_in[0];
    const int*   ho_src = (const int*)d_in[2];
    const int*   ho_dst = (const int*)d_in[3];
    const float* ho_w   = (const float*)d_in[4];
    const int*   bi_src = (const int*)d_in[8];
    const int*   bi_dst = (const int*)d_in[9];
    const float* W220   = (const float*)d_in[12];
    const float* b220   = (const float*)d_in[13];
    const float* W221   = (const float*)d_in[14];
    const float* b221   = (const float*)d_in[15];
    const float* lin1_w = (const float*)d_in[20];
    const float* lin1_b = (const float*)d_in[21];
    const float* mlp_w  = (const float*)d_in[24];
    const float* mlp_b  = (const float*)d_in[25];

    const int NHO = in_sizes[0] / 60;
    const int EHO = in_sizes[2];
    const int EBI = in_sizes[8];
    const int NFO = out_size / 10;

    char* ws = (char*)d_ws;
    float* dinv = (float*)ws;                                       // NHO floats
    float* A = (float*)(ws + (size_t)NHO * 4);                      // NHO*32 floats
    float* B = (float*)(ws + (size_t)NHO * 4 + (size_t)NHO * 32 * 4); // NHO*32 floats
    float* out = (float*)d_out;

    const int BLK = 256;
    auto blocks = [&](long long n) {
        long long b = (n + BLK - 1) / BLK;
        return (int)(b > 4096 ? 4096 : b);
    };

    // degree -> dinv
    hipMemsetAsync(dinv, 0, (size_t)NHO * 4, stream);
    k_deg<<<blocks(EHO), BLK, 0, stream>>>(ho_dst, ho_w, dinv, EHO);
    k_dinv<<<blocks(NHO), BLK, 0, stream>>>(dinv, NHO);

    // layer 1: xw1 -> A[.,16]; agg -> B; h=elu(...) in B
    k_xw<60, 16><<<blocks(NHO), BLK, 0, stream>>>(x_ho, W220, A, NHO, nullptr);
    hipMemsetAsync(B, 0, (size_t)NHO * 16 * 4, stream);
    k_edge<16><<<blocks(EHO), BLK, 0, stream>>>(ho_src, ho_dst, ho_w, dinv, A, B, EHO);
    k_combine<16><<<blocks((long long)NHO * 16), BLK, 0, stream>>>(B, A, dinv, b220, NHO);

    // layer 2: xw2 = h @ W221 -> A[.,32]; agg -> B; h2 in B
    k_xw<16, 32><<<blocks(NHO), BLK, 0, stream>>>(B, W221, A, NHO, nullptr);
    hipMemsetAsync(B, 0, (size_t)NHO * 32 * 4, stream);
    k_edge<32><<<blocks(EHO), BLK, 0, stream>>>(ho_src, ho_dst, ho_w, dinv, A, B, EHO);
    k_combine<32><<<blocks((long long)NHO * 32), BLK, 0, stream>>>(B, A, dinv, b221, NHO);

    // m = h2 @ lin1_w + lin1_b -> A[.,32]
    k_xw<32, 32><<<blocks(NHO), BLK, 0, stream>>>(B, lin1_w, A, NHO, lin1_b);

    // bipartite scatter: aggbi -> B[.,32] (first NFO rows)
    hipMemsetAsync(B, 0, (size_t)NFO * 32 * 4, stream);
    k_bi<<<blocks(EBI), BLK, 0, stream>>>(bi_src, bi_dst, A, B, EBI);

    // out = elu(aggbi) @ mlp_w + mlp_b
    k_out<<<blocks(NFO), BLK, 0, stream>>>(B, mlp_w, mlp_b, out, NFO);
}

// Round 2
// 2257.935 us; speedup vs baseline: 5.5537x; 5.5537x over previous
//
#include <hip/hip_runtime.h>
#include <math.h>

static __device__ __forceinline__ float elu_f(float x) {
    return x > 0.0f ? x : expm1f(x);
}

// ---------------- common small kernels ----------------

__global__ void k_deg_hist(const int* __restrict__ dst, const float* __restrict__ w,
                           float* __restrict__ deg, int* __restrict__ cnt, int E) {
    int i = blockIdx.x * blockDim.x + threadIdx.x;
    int stride = gridDim.x * blockDim.x;
    for (; i < E; i += stride) {
        int d = dst[i];
        atomicAdd(&deg[d], w[i]);
        atomicAdd(&cnt[d], 1);
    }
}

__global__ void k_hist(const int* __restrict__ dst, int* __restrict__ cnt, int E) {
    int i = blockIdx.x * blockDim.x + threadIdx.x;
    int stride = gridDim.x * blockDim.x;
    for (; i < E; i += stride) atomicAdd(&cnt[dst[i]], 1);
}

__global__ void k_dinv(float* __restrict__ deg, int N) {
    int i = blockIdx.x * blockDim.x + threadIdx.x;
    int stride = gridDim.x * blockDim.x;
    for (; i < N; i += stride) deg[i] = rsqrtf(deg[i] + 1.0f);
}

// ---------------- two-level exclusive scan (N <= 1024*1024) ----------------
#define SCAN_BLOCK 1024

__global__ void k_scan_block(const int* __restrict__ in, int* __restrict__ out,
                             int* __restrict__ sums, int n) {
    __shared__ int tmp[SCAN_BLOCK];
    int gid = blockIdx.x * SCAN_BLOCK + threadIdx.x;
    int v = (gid < n) ? in[gid] : 0;
    tmp[threadIdx.x] = v;
    __syncthreads();
    for (int off = 1; off < SCAN_BLOCK; off <<= 1) {
        int t = (threadIdx.x >= off) ? tmp[threadIdx.x - off] : 0;
        __syncthreads();
        tmp[threadIdx.x] += t;
        __syncthreads();
    }
    if (gid < n) out[gid] = tmp[threadIdx.x] - v;   // exclusive
    if (threadIdx.x == SCAN_BLOCK - 1) sums[blockIdx.x] = tmp[threadIdx.x];
}

__global__ void k_scan_sums(int* __restrict__ sums, int nb) {
    __shared__ int tmp[SCAN_BLOCK];
    int v = (threadIdx.x < nb) ? sums[threadIdx.x] : 0;
    tmp[threadIdx.x] = v;
    __syncthreads();
    for (int off = 1; off < SCAN_BLOCK; off <<= 1) {
        int t = (threadIdx.x >= off) ? tmp[threadIdx.x - off] : 0;
        __syncthreads();
        tmp[threadIdx.x] += t;
        __syncthreads();
    }
    if (threadIdx.x < nb) sums[threadIdx.x] = tmp[threadIdx.x] - v;  // exclusive
}

__global__ void k_scan_add(int* __restrict__ out, const int* __restrict__ sums,
                           int n, int total) {
    int gid = blockIdx.x * SCAN_BLOCK + threadIdx.x;
    if (gid < n) out[gid] += sums[blockIdx.x];
    if (gid == 0) out[n] = total;
}

// ---------------- CSR fill ----------------

__global__ void k_fill_ho(const int* __restrict__ src, const int* __restrict__ dst,
                          const float* __restrict__ w, const float* __restrict__ dinv,
                          const int* __restrict__ rs, int* __restrict__ cursor,
                          int2* __restrict__ pairs, int E) {
    int e = blockIdx.x * blockDim.x + threadIdx.x;
    int stride = gridDim.x * blockDim.x;
    for (; e < E; e += stride) {
        int d = dst[e], s = src[e];
        int pos = atomicAdd(&cursor[d], 1);
        pairs[rs[d] + pos] = make_int2(s, __float_as_int(dinv[s] * w[e]));
    }
}

__global__ void k_fill_bi(const int* __restrict__ src, const int* __restrict__ dst,
                          const int* __restrict__ rs, int* __restrict__ cursor,
                          int* __restrict__ out, int E) {
    int e = blockIdx.x * blockDim.x + threadIdx.x;
    int stride = gridDim.x * blockDim.x;
    for (; e < E; e += stride) {
        int d = dst[e];
        int pos = atomicAdd(&cursor[d], 1);
        out[rs[d] + pos] = src[e];
    }
}

// ---------------- dense per-node matvec ----------------

template<int IN, int OUT>
__global__ void k_xw(const float* __restrict__ x, const float* __restrict__ W,
                     float* __restrict__ y, int N, const float* __restrict__ bias) {
    __shared__ float sW[IN * OUT];
    __shared__ float sb[OUT];
    for (int t = threadIdx.x; t < IN * OUT; t += blockDim.x) sW[t] = W[t];
    if (threadIdx.x < OUT) sb[threadIdx.x] = bias ? bias[threadIdx.x] : 0.0f;
    __syncthreads();
    int i = blockIdx.x * blockDim.x + threadIdx.x;
    int stride = gridDim.x * blockDim.x;
    for (; i < N; i += stride) {
        const float* xr = x + (size_t)i * IN;
        float acc[OUT];
        #pragma unroll
        for (int o = 0; o < OUT; o++) acc[o] = sb[o];
        #pragma unroll
        for (int k = 0; k < IN; k++) {
            float xv = xr[k];
            #pragma unroll
            for (int o = 0; o < OUT; o++) acc[o] += xv * sW[k * OUT + o];
        }
        float* yr = y + (size_t)i * OUT;
        #pragma unroll
        for (int o = 0; o < OUT; o++) yr[o] = acc[o];
    }
}

// ---------------- CSR gather: h = elu(dinv*sum + xw*dinv^2 + b) ----------------

template<int F, int SHIFT>
__global__ void k_gather(const int2* __restrict__ pairs, const int* __restrict__ rs,
                         const float* __restrict__ dinv, const float* __restrict__ xw,
                         const float* __restrict__ bias, float* __restrict__ out, int N) {
    int t = blockIdx.x * blockDim.x + threadIdx.x;
    int node = t >> SHIFT;
    int lane = t & (F - 1);
    if (node >= N) return;
    int beg = rs[node], end = rs[node + 1];
    float acc = 0.0f;
    for (int k = beg; k < end; k++) {
        int2 p = pairs[k];
        acc += __int_as_float(p.y) * xw[(size_t)p.x * F + lane];
    }
    float di = dinv[node];
    float v = di * acc + xw[(size_t)node * F + lane] * di * di + bias[lane];
    out[(size_t)node * F + lane] = elu_f(v);
}

// bipartite gather (no weights, no self-loop): out[i,f] = sum_src m[src,f]
__global__ void k_bi_gather(const int* __restrict__ srcs, const int* __restrict__ rs,
                            const float* __restrict__ m, float* __restrict__ out, int N) {
    int t = blockIdx.x * blockDim.x + threadIdx.x;
    int node = t >> 5;
    int lane = t & 31;
    if (node >= N) return;
    int beg = rs[node], end = rs[node + 1];
    float acc = 0.0f;
    for (int k = beg; k < end; k++)
        acc += m[(size_t)srcs[k] * 32 + lane];
    out[(size_t)node * 32 + lane] = acc;
}

// out[i,:] = elu(agg[i,:]) @ mlp_w + mlp_b
__global__ void k_out(const float* __restrict__ agg, const float* __restrict__ W,
                      const float* __restrict__ b, float* __restrict__ out, int N) {
    __shared__ float sW[32 * 10];
    __shared__ float sb[10];
    for (int t = threadIdx.x; t < 320; t += blockDim.x) sW[t] = W[t];
    if (threadIdx.x < 10) sb[threadIdx.x] = b[threadIdx.x];
    __syncthreads();
    int i = blockIdx.x * blockDim.x + threadIdx.x;
    int stride = gridDim.x * blockDim.x;
    for (; i < N; i += stride) {
        const float* ar = agg + (size_t)i * 32;
        float acc[10];
        #pragma unroll
        for (int c = 0; c < 10; c++) acc[c] = sb[c];
        #pragma unroll
        for (int k = 0; k < 32; k++) {
            float a = elu_f(ar[k]);
            #pragma unroll
            for (int c = 0; c < 10; c++) acc[c] += a * sW[k * 10 + c];
        }
        float* orow = out + (size_t)i * 10;
        #pragma unroll
        for (int c = 0; c < 10; c++) acc[c] = acc[c];  // keep
        #pragma unroll
        for (int c = 0; c < 10; c++) orow[c] = acc[c];
    }
}

// ---------------- fallback (atomic scatter) kernels ----------------

template<int F>
__global__ void k_edge(const int* __restrict__ src, const int* __restrict__ dst,
                       const float* __restrict__ w, const float* __restrict__ dinv,
                       const float* __restrict__ xw, float* __restrict__ agg, int E) {
    int e = blockIdx.x * blockDim.x + threadIdx.x;
    int stride = gridDim.x * blockDim.x;
    for (; e < E; e += stride) {
        int s = src[e], d = dst[e];
        float c = dinv[s] * w[e] * dinv[d];
        const float4* xs = (const float4*)(xw + (size_t)s * F);
        float* ad = agg + (size_t)d * F;
        #pragma unroll
        for (int f = 0; f < F / 4; f++) {
            float4 v = xs[f];
            atomicAdd(&ad[4 * f + 0], v.x * c);
            atomicAdd(&ad[4 * f + 1], v.y * c);
            atomicAdd(&ad[4 * f + 2], v.z * c);
            atomicAdd(&ad[4 * f + 3], v.w * c);
        }
    }
}

template<int F>
__global__ void k_combine(float* __restrict__ agg, const float* __restrict__ xw,
                          const float* __restrict__ dinv, const float* __restrict__ b,
                          int N) {
    int idx = blockIdx.x * blockDim.x + threadIdx.x;
    int stride = gridDim.x * blockDim.x;
    int total = N * F;
    for (; idx < total; idx += stride) {
        int i = idx / F, f = idx & (F - 1);
        float di = dinv[i];
        float v = agg[idx] + xw[idx] * di * di + b[f];
        agg[idx] = elu_f(v);
    }
}

__global__ void k_bi(const int* __restrict__ src, const int* __restrict__ dst,
                     const float* __restrict__ m, float* __restrict__ agg, int E) {
    int e = blockIdx.x * blockDim.x + threadIdx.x;
    int stride = gridDim.x * blockDim.x;
    for (; e < E; e += stride) {
        int s = src[e], d = dst[e];
        const float4* ms = (const float4*)(m + (size_t)s * 32);
        float* ad = agg + (size_t)d * 32;
        #pragma unroll
        for (int f = 0; f < 8; f++) {
            float4 v = ms[f];
            atomicAdd(&ad[4 * f + 0], v.x);
            atomicAdd(&ad[4 * f + 1], v.y);
            atomicAdd(&ad[4 * f + 2], v.z);
            atomicAdd(&ad[4 * f + 3], v.w);
        }
    }
}

// ---------------- launch ----------------

extern "C" void kernel_launch(void* const* d_in, const int* in_sizes, int n_in,
                              void* d_out, int out_size, void* d_ws, size_t ws_size,
                              hipStream_t stream) {
    const float* x_ho   = (const float*)d_in[0];
    const int*   ho_src = (const int*)d_in[2];
    const int*   ho_dst = (const int*)d_in[3];
    const float* ho_w   = (const float*)d_in[4];
    const int*   bi_src = (const int*)d_in[8];
    const int*   bi_dst = (const int*)d_in[9];
    const float* W220   = (const float*)d_in[12];
    const float* b220   = (const float*)d_in[13];
    const float* W221   = (const float*)d_in[14];
    const float* b221   = (const float*)d_in[15];
    const float* lin1_w = (const float*)d_in[20];
    const float* lin1_b = (const float*)d_in[21];
    const float* mlp_w  = (const float*)d_in[24];
    const float* mlp_b  = (const float*)d_in[25];

    const int NHO = in_sizes[0] / 60;
    const int EHO = in_sizes[2];
    const int EBI = in_sizes[8];
    const int NFO = out_size / 10;

    const int BLK = 256;
    auto blocks = [&](long long n) {
        long long b = (n + BLK - 1) / BLK;
        return (int)(b > 4096 ? 4096 : b);
    };
    float* out = (float*)d_out;

    // ---- workspace layout (4-byte words) ----
    size_t off = 0;
    float* ws = (float*)d_ws;
    float* dinv  = ws + off; off += NHO;
    float* A     = ws + off; off += (size_t)NHO * 32;
    float* B     = ws + off; off += (size_t)NHO * 32;
    int*   rs_ho = (int*)(ws + off); off += NHO + 1;
    off = (off + 1) & ~(size_t)1;               // 8B align for int2
    int2*  pairs = (int2*)(ws + off); off += (size_t)EHO * 2;
    int*   rs_bi = (int*)(ws + off); off += NFO + 1;
    int*   srcbi = (int*)(ws + off); off += EBI;
    int*   cnt   = (int*)(ws + off); off += (NHO > NFO ? NHO : NFO) + 1;
    int*   bsums = (int*)(ws + off); off += SCAN_BLOCK;
    size_t needed = off * 4;

    if (ws_size >= needed) {
        // ======== CSR gather path ========
        const int nbHO = (NHO + SCAN_BLOCK - 1) / SCAN_BLOCK;
        const int nbBI = (NFO + SCAN_BLOCK - 1) / SCAN_BLOCK;

        // degree + histogram
        hipMemsetAsync(dinv, 0, (size_t)NHO * 4, stream);
        hipMemsetAsync(cnt, 0, (size_t)NHO * 4, stream);
        k_deg_hist<<<blocks(EHO), BLK, 0, stream>>>(ho_dst, ho_w, dinv, cnt, EHO);
        k_dinv<<<blocks(NHO), BLK, 0, stream>>>(dinv, NHO);

        // HO CSR
        k_scan_block<<<nbHO, SCAN_BLOCK, 0, stream>>>(cnt, rs_ho, bsums, NHO);
        k_scan_sums<<<1, SCAN_BLOCK, 0, stream>>>(bsums, nbHO);
        k_scan_add<<<nbHO, SCAN_BLOCK, 0, stream>>>(rs_ho, bsums, NHO, EHO);
        hipMemsetAsync(cnt, 0, (size_t)NHO * 4, stream);
        k_fill_ho<<<blocks(EHO), BLK, 0, stream>>>(ho_src, ho_dst, ho_w, dinv,
                                                   rs_ho, cnt, pairs, EHO);

        // BI CSR
        hipMemsetAsync(cnt, 0, (size_t)NFO * 4, stream);
        k_hist<<<blocks(EBI), BLK, 0, stream>>>(bi_dst, cnt, EBI);
        k_scan_block<<<nbBI, SCAN_BLOCK, 0, stream>>>(cnt, rs_bi, bsums, NFO);
        k_scan_sums<<<1, SCAN_BLOCK, 0, stream>>>(bsums, nbBI);
        k_scan_add<<<nbBI, SCAN_BLOCK, 0, stream>>>(rs_bi, bsums, NFO, EBI);
        hipMemsetAsync(cnt, 0, (size_t)NFO * 4, stream);
        k_fill_bi<<<blocks(EBI), BLK, 0, stream>>>(bi_src, bi_dst, rs_bi, cnt, srcbi, EBI);

        // layer 1: A = x_ho @ W220 ; B = elu(gcn)
        k_xw<60, 16><<<blocks(NHO), BLK, 0, stream>>>(x_ho, W220, A, NHO, nullptr);
        {
            long long t = (long long)NHO * 16;
            k_gather<16, 4><<<(int)((t + BLK - 1) / BLK), BLK, 0, stream>>>(
                pairs, rs_ho, dinv, A, b220, B, NHO);
        }
        // layer 2
        k_xw<16, 32><<<blocks(NHO), BLK, 0, stream>>>(B, W221, A, NHO, nullptr);
        {
            long long t = (long long)NHO * 32;
            k_gather<32, 5><<<(int)((t + BLK - 1) / BLK), BLK, 0, stream>>>(
                pairs, rs_ho, dinv, A, b221, B, NHO);
        }
        // m = h2 @ lin1_w + lin1_b
        k_xw<32, 32><<<blocks(NHO), BLK, 0, stream>>>(B, lin1_w, A, NHO, lin1_b);
        // bipartite gather into B (reuse), then MLP head
        {
            long long t = (long long)NFO * 32;
            k_bi_gather<<<(int)((t + BLK - 1) / BLK), BLK, 0, stream>>>(
                srcbi, rs_bi, A, B, NFO);
        }
        k_out<<<blocks(NFO), BLK, 0, stream>>>(B, mlp_w, mlp_b, out, NFO);
    } else {
        // ======== fallback: verified atomic path ========
        hipMemsetAsync(dinv, 0, (size_t)NHO * 4, stream);
        k_deg_hist<<<blocks(EHO), BLK, 0, stream>>>(ho_dst, ho_w, dinv, (int*)B, EHO);
        k_dinv<<<blocks(NHO), BLK, 0, stream>>>(dinv, NHO);

        k_xw<60, 16><<<blocks(NHO), BLK, 0, stream>>>(x_ho, W220, A, NHO, nullptr);
        hipMemsetAsync(B, 0, (size_t)NHO * 16 * 4, stream);
        k_edge<16><<<blocks(EHO), BLK, 0, stream>>>(ho_src, ho_dst, ho_w, dinv, A, B, EHO);
        k_combine<16><<<blocks((long long)NHO * 16), BLK, 0, stream>>>(B, A, dinv, b220, NHO);

        k_xw<16, 32><<<blocks(NHO), BLK, 0, stream>>>(B, W221, A, NHO, nullptr);
        hipMemsetAsync(B, 0, (size_t)NHO * 32 * 4, stream);
        k_edge<32><<<blocks(EHO), BLK, 0, stream>>>(ho_src, ho_dst, ho_w, dinv, A, B, EHO);
        k_combine<32><<<blocks((long long)NHO * 32), BLK, 0, stream>>>(B, A, dinv, b221, NHO);

        k_xw<32, 32><<<blocks(NHO), BLK, 0, stream>>>(B, lin1_w, A, NHO, lin1_b);
        hipMemsetAsync(B, 0, (size_t)NFO * 32 * 4, stream);
        k_bi<<<blocks(EBI), BLK, 0, stream>>>(bi_src, bi_dst, A, B, EBI);
        k_out<<<blocks(NFO), BLK, 0, stream>>>(B, mlp_w, mlp_b, out, NFO);
    }
}

// Round 3
// 1077.505 us; speedup vs baseline: 11.6380x; 2.0955x over previous
//
#include <hip/hip_runtime.h>
#include <math.h>

static __device__ __forceinline__ float elu_f(float x) {
    return x > 0.0f ? x : expm1f(x);
}

// ---------------- histogram: HO deg+cnt, BI cnt, in one pass ----------------

__global__ void k_hist_all(const int* __restrict__ ho_dst, const float* __restrict__ ho_w,
                           const int* __restrict__ bi_dst,
                           float* __restrict__ deg, int* __restrict__ cntHO,
                           int* __restrict__ cntBI, int Eho, int Ebi) {
    int i = blockIdx.x * blockDim.x + threadIdx.x;
    int stride = gridDim.x * blockDim.x;
    int E = Eho > Ebi ? Eho : Ebi;
    for (; i < E; i += stride) {
        if (i < Eho) {
            int d = ho_dst[i];
            atomicAdd(&deg[d], ho_w[i]);
            atomicAdd(&cntHO[d], 1);
        }
        if (i < Ebi) atomicAdd(&cntBI[bi_dst[i]], 1);
    }
}

// ---------------- two-level exclusive scan ----------------
#define SCAN_BLOCK 1024

__global__ void k_scan_block(const int* __restrict__ in, int* __restrict__ out,
                             int* __restrict__ sums, int n, float* __restrict__ deg_dinv) {
    __shared__ int tmp[SCAN_BLOCK];
    int gid = blockIdx.x * SCAN_BLOCK + threadIdx.x;
    int v = (gid < n) ? in[gid] : 0;
    tmp[threadIdx.x] = v;
    __syncthreads();
    for (int off = 1; off < SCAN_BLOCK; off <<= 1) {
        int t = (threadIdx.x >= off) ? tmp[threadIdx.x - off] : 0;
        __syncthreads();
        tmp[threadIdx.x] += t;
        __syncthreads();
    }
    if (gid < n) {
        out[gid] = tmp[threadIdx.x] - v;   // exclusive
        if (deg_dinv) deg_dinv[gid] = rsqrtf(deg_dinv[gid] + 1.0f);  // fold dinv
    }
    if (threadIdx.x == SCAN_BLOCK - 1) sums[blockIdx.x] = tmp[threadIdx.x];
}

__global__ void k_scan_sums(int* __restrict__ sums, int nb) {
    __shared__ int tmp[SCAN_BLOCK];
    int v = (threadIdx.x < nb) ? sums[threadIdx.x] : 0;
    tmp[threadIdx.x] = v;
    __syncthreads();
    for (int off = 1; off < SCAN_BLOCK; off <<= 1) {
        int t = (threadIdx.x >= off) ? tmp[threadIdx.x - off] : 0;
        __syncthreads();
        tmp[threadIdx.x] += t;
        __syncthreads();
    }
    if (threadIdx.x < nb) sums[threadIdx.x] = tmp[threadIdx.x] - v;  // exclusive
}

__global__ void k_scan_add(int* __restrict__ out, const int* __restrict__ sums,
                           int n, int total) {
    int gid = blockIdx.x * SCAN_BLOCK + threadIdx.x;
    if (gid < n) out[gid] += sums[blockIdx.x];
    if (gid == 0) out[n] = total;
}

// ---------------- CSR fill, both graphs in one pass ----------------

__global__ void k_fill_all(const int* __restrict__ hs, const int* __restrict__ hd,
                           const float* __restrict__ hw, const float* __restrict__ dinv,
                           const int* __restrict__ rsho, int* __restrict__ curHO,
                           int2* __restrict__ pairs,
                           const int* __restrict__ bs, const int* __restrict__ bd,
                           const int* __restrict__ rsbi, int* __restrict__ curBI,
                           int* __restrict__ srcbi, int Eho, int Ebi) {
    int i = blockIdx.x * blockDim.x + threadIdx.x;
    int stride = gridDim.x * blockDim.x;
    int E = Eho > Ebi ? Eho : Ebi;
    for (; i < E; i += stride) {
        if (i < Eho) {
            int d = hd[i], s = hs[i];
            int pos = atomicAdd(&curHO[d], 1);
            pairs[rsho[d] + pos] = make_int2(s, __float_as_int(dinv[s] * hw[i]));
        }
        if (i < Ebi) {
            int d = bd[i];
            int pos = atomicAdd(&curBI[d], 1);
            srcbi[rsbi[d] + pos] = bs[i];
        }
    }
}

// ---------------- A = x @ W220 : LDS-staged, coalesced ----------------
// 128 rows per 128-thread block; x rows contiguous -> cooperative float4 load.

__global__ __launch_bounds__(128) void k_xw60(const float* __restrict__ x,
                                              const float* __restrict__ W,
                                              float* __restrict__ y, int N) {
    __shared__ float sx[128 * 61];     // pad 61: odd stride -> conflict-free reads
    __shared__ float sW[60 * 16];
    for (int t = threadIdx.x; t < 960; t += 128) sW[t] = W[t];
    int base = blockIdx.x * 128;
    int rows = N - base; if (rows > 128) rows = 128;
    const float4* xg = (const float4*)(x + (size_t)base * 60);
    int nf4 = rows * 15;               // 60 floats = 15 aligned float4 per row
    for (int j = threadIdx.x; j < nf4; j += 128) {
        float4 v = xg[j];
        int r = j / 15, k4 = j % 15;
        float* dst = &sx[r * 61 + k4 * 4];
        dst[0] = v.x; dst[1] = v.y; dst[2] = v.z; dst[3] = v.w;
    }
    __syncthreads();
    int t = threadIdx.x;
    if (t < rows) {
        const float* xr = &sx[t * 61];
        float acc[16];
        #pragma unroll
        for (int o = 0; o < 16; o++) acc[o] = 0.0f;
        #pragma unroll
        for (int k = 0; k < 60; k++) {
            float xv = xr[k];
            #pragma unroll
            for (int o = 0; o < 16; o++) acc[o] += xv * sW[k * 16 + o];
        }
        float4* yr = (float4*)(y + (size_t)(base + t) * 16);
        yr[0] = make_float4(acc[0], acc[1], acc[2], acc[3]);
        yr[1] = make_float4(acc[4], acc[5], acc[6], acc[7]);
        yr[2] = make_float4(acc[8], acc[9], acc[10], acc[11]);
        yr[3] = make_float4(acc[12], acc[13], acc[14], acc[15]);
    }
}

// ---------------- layer-1 gather: B = elu(dinv*sum + A*dinv^2 + b220) ----------------
// 16 lanes per node, lane = feature.

__global__ void k_gather1(const int2* __restrict__ pairs, const int* __restrict__ rs,
                          const float* __restrict__ dinv, const float* __restrict__ A,
                          const float* __restrict__ b, float* __restrict__ B, int N) {
    int t = blockIdx.x * blockDim.x + threadIdx.x;
    int node = t >> 4, ln = t & 15;
    if (node >= N) return;
    int beg = rs[node], end = rs[node + 1];
    float acc = 0.0f;
    for (int k = beg; k < end; k++) {
        int2 p = pairs[k];
        acc += __int_as_float(p.y) * A[(size_t)p.x * 16 + ln];
    }
    float di = dinv[node];
    float v = fmaf(di, acc, fmaf(A[(size_t)node * 16 + ln], di * di, b[ln]));
    B[(size_t)node * 16 + ln] = elu_f(v);
}

// ---------------- layer-2 gather fused with W221 + lin1 ----------------
// agg16 = dinv*sum(pairs·B[src]) + B[i]*dinv^2    (16-dim, pre-W221: linearity)
// h2    = elu(agg16 @ W221 + b221)                (32-dim, via 16-lane shfl)
// m     = h2 @ lin1_w + lin1_b                    (32-dim)

__global__ void k_gather2(const int2* __restrict__ pairs, const int* __restrict__ rs,
                          const float* __restrict__ dinv, const float* __restrict__ B,
                          const float* __restrict__ W221, const float* __restrict__ b221,
                          const float* __restrict__ L1w, const float* __restrict__ L1b,
                          float* __restrict__ M, int N) {
    __shared__ float sW[16 * 32];
    __shared__ float sb2[32];
    __shared__ float sL[32 * 32];
    __shared__ float sLb[32];
    for (int t = threadIdx.x; t < 512; t += blockDim.x) sW[t] = W221[t];
    for (int t = threadIdx.x; t < 1024; t += blockDim.x) sL[t] = L1w[t];
    if (threadIdx.x < 32) { sb2[threadIdx.x] = b221[threadIdx.x]; sLb[threadIdx.x] = L1b[threadIdx.x]; }
    __syncthreads();
    int t = blockIdx.x * blockDim.x + threadIdx.x;
    int node = t >> 4, ln = t & 15;
    if (node >= N) return;
    int beg = rs[node], end = rs[node + 1];
    float acc = 0.0f;
    for (int k = beg; k < end; k++) {
        int2 p = pairs[k];
        acc += __int_as_float(p.y) * B[(size_t)p.x * 16 + ln];
    }
    float di = dinv[node];
    float agg = fmaf(di, acc, B[(size_t)node * 16 + ln] * di * di);
    // h2 = elu(agg @ W221 + b221): lane ln owns outputs ln and ln+16
    float h2a = sb2[ln], h2b = sb2[ln + 16];
    #pragma unroll
    for (int k = 0; k < 16; k++) {
        float ak = __shfl(agg, k, 16);
        h2a += ak * sW[k * 32 + ln];
        h2b += ak * sW[k * 32 + ln + 16];
    }
    h2a = elu_f(h2a); h2b = elu_f(h2b);
    // m = h2 @ lin1 + lin1_b
    float m0 = sLb[ln], m1 = sLb[ln + 16];
    #pragma unroll
    for (int k = 0; k < 16; k++) {
        float a0 = __shfl(h2a, k, 16);
        float a1 = __shfl(h2b, k, 16);
        m0 += a0 * sL[k * 32 + ln]        + a1 * sL[(k + 16) * 32 + ln];
        m1 += a0 * sL[k * 32 + ln + 16]   + a1 * sL[(k + 16) * 32 + ln + 16];
    }
    float* mr = M + (size_t)node * 32;
    mr[ln] = m0; mr[ln + 16] = m1;
}

// ---------------- bipartite gather fused with MLP head ----------------
// 32 lanes per node; out[i,:] = elu(sum_src m[src,:]) @ mlp_w + mlp_b

__global__ void k_bi_mlp(const int* __restrict__ srcs, const int* __restrict__ rs,
                         const float* __restrict__ M, const float* __restrict__ mw,
                         const float* __restrict__ mb, float* __restrict__ out, int N) {
    __shared__ float sW[32 * 10];
    __shared__ float sb[10];
    for (int t = threadIdx.x; t < 320; t += blockDim.x) sW[t] = mw[t];
    if (threadIdx.x < 10) sb[threadIdx.x] = mb[threadIdx.x];
    __syncthreads();
    int t = blockIdx.x * blockDim.x + threadIdx.x;
    int node = t >> 5, ln = t & 31;
    if (node >= N) return;
    int beg = rs[node], end = rs[node + 1];
    float acc = 0.0f;
    for (int k = beg; k < end; k++)
        acc += M[(size_t)srcs[k] * 32 + ln];
    float e = elu_f(acc);
    int lw = ln < 10 ? ln : 0;          // keep sW index in bounds for masked lanes
    float o = ln < 10 ? sb[ln] : 0.0f;
    #pragma unroll
    for (int k = 0; k < 32; k++) {
        float ak = __shfl(e, k, 32);
        o += ak * sW[k * 10 + lw];
    }
    if (ln < 10) out[(size_t)node * 10 + ln] = o;
}

// ---------------- launch ----------------

extern "C" void kernel_launch(void* const* d_in, const int* in_sizes, int n_in,
                              void* d_out, int out_size, void* d_ws, size_t ws_size,
                              hipStream_t stream) {
    const float* x_ho   = (const float*)d_in[0];
    const int*   ho_src = (const int*)d_in[2];
    const int*   ho_dst = (const int*)d_in[3];
    const float* ho_w   = (const float*)d_in[4];
    const int*   bi_src = (const int*)d_in[8];
    const int*   bi_dst = (const int*)d_in[9];
    const float* W220   = (const float*)d_in[12];
    const float* b220   = (const float*)d_in[13];
    const float* W221   = (const float*)d_in[14];
    const float* b221   = (const float*)d_in[15];
    const float* lin1_w = (const float*)d_in[20];
    const float* lin1_b = (const float*)d_in[21];
    const float* mlp_w  = (const float*)d_in[24];
    const float* mlp_b  = (const float*)d_in[25];

    const int NHO = in_sizes[0] / 60;
    const int EHO = in_sizes[2];
    const int EBI = in_sizes[8];
    const int NFO = out_size / 10;
    float* out = (float*)d_out;

    // ---- workspace layout (4-byte words); M overlays A (dead by then) ----
    size_t off = 0;
    float* ws = (float*)d_ws;
    float* dinv  = ws + off; off += NHO;                 // deg -> dinv in place
    float* A     = ws + off; off += (size_t)NHO * 32;    // xw1 uses 16; M uses all 32
    float* M     = A;
    float* B     = ws + off; off += (size_t)NHO * 16;
    int*   rs_ho = (int*)(ws + off); off += NHO + 1;
    off = (off + 1) & ~(size_t)1;                        // 8B align
    int2*  pairs = (int2*)(ws + off); off += (size_t)EHO * 2;
    int*   rs_bi = (int*)(ws + off); off += NFO + 1;
    int*   srcbi = (int*)(ws + off); off += EBI;
    int*   cntHO = (int*)(ws + off); off += NHO;
    int*   curHO = (int*)(ws + off); off += NHO;
    int*   cntBI = (int*)(ws + off); off += NFO;
    int*   curBI = (int*)(ws + off); off += NFO;
    int*   bsums = (int*)(ws + off); off += SCAN_BLOCK;

    const int BLK = 256;
    auto blocks = [&](long long n) {
        long long b = (n + BLK - 1) / BLK;
        return (int)(b > 4096 ? 4096 : b);
    };
    const int nbHO = (NHO + SCAN_BLOCK - 1) / SCAN_BLOCK;
    const int nbBI = (NFO + SCAN_BLOCK - 1) / SCAN_BLOCK;

    // zero deg and the cnt/cursor block (contiguous)
    hipMemsetAsync(dinv, 0, (size_t)NHO * 4, stream);
    hipMemsetAsync(cntHO, 0, ((size_t)2 * NHO + 2 * NFO) * 4, stream);

    // histograms (HO deg+cnt, BI cnt)
    k_hist_all<<<blocks(EHO > EBI ? EHO : EBI), BLK, 0, stream>>>(
        ho_dst, ho_w, bi_dst, dinv, cntHO, cntBI, EHO, EBI);

    // scans (dinv folded into HO scan)
    k_scan_block<<<nbHO, SCAN_BLOCK, 0, stream>>>(cntHO, rs_ho, bsums, NHO, dinv);
    k_scan_sums<<<1, SCAN_BLOCK, 0, stream>>>(bsums, nbHO);
    k_scan_add<<<nbHO, SCAN_BLOCK, 0, stream>>>(rs_ho, bsums, NHO, EHO);
    k_scan_block<<<nbBI, SCAN_BLOCK, 0, stream>>>(cntBI, rs_bi, bsums, NFO, nullptr);
    k_scan_sums<<<1, SCAN_BLOCK, 0, stream>>>(bsums, nbBI);
    k_scan_add<<<nbBI, SCAN_BLOCK, 0, stream>>>(rs_bi, bsums, NFO, EBI);

    // CSR fill (both graphs)
    k_fill_all<<<blocks(EHO > EBI ? EHO : EBI), BLK, 0, stream>>>(
        ho_src, ho_dst, ho_w, dinv, rs_ho, curHO, pairs,
        bi_src, bi_dst, rs_bi, curBI, srcbi, EHO, EBI);

    // A = x @ W220
    k_xw60<<<(NHO + 127) / 128, 128, 0, stream>>>(x_ho, W220, A, NHO);

    // B = elu(gcn1)
    {
        long long t = (long long)NHO * 16;
        k_gather1<<<(int)((t + BLK - 1) / BLK), BLK, 0, stream>>>(
            pairs, rs_ho, dinv, A, b220, B, NHO);
    }
    // M = (elu(gcn2)) @ lin1 + lin1_b   (aggregate-then-transform)
    {
        long long t = (long long)NHO * 16;
        k_gather2<<<(int)((t + BLK - 1) / BLK), BLK, 0, stream>>>(
            pairs, rs_ho, dinv, B, W221, b221, lin1_w, lin1_b, M, NHO);
    }
    // out = elu(bipartite sum of M) @ mlp_w + mlp_b
    {
        long long t = (long long)NFO * 32;
        k_bi_mlp<<<(int)((t + BLK - 1) / BLK), BLK, 0, stream>>>(
            srcbi, rs_bi, M, mlp_w, mlp_b, out, NFO);
    }
}

// Round 4
// 837.249 us; speedup vs baseline: 14.9776x; 1.2870x over previous
//
#include <hip/hip_runtime.h>
#include <math.h>

static __device__ __forceinline__ float elu_f(float x) {
    return x > 0.0f ? x : expm1f(x);
}

#define FXSCALE 67108864.0f              // 2^26 fixed-point scale for weight sums
#define FXMASK  ((1ULL << 40) - 1)

// ---------------- pass 1: packed histogram + rank capture ----------------
// HO: one 64-bit atomic per edge: bits[40:63] = count, bits[0:39] = fx weight sum.
// Return value gives this edge's within-node rank -> fill pass needs no atomics.

__global__ void k_hist(const int* __restrict__ hd, const float* __restrict__ hw,
                       const int* __restrict__ bd,
                       unsigned long long* __restrict__ packed, int* __restrict__ cntBI,
                       unsigned short* __restrict__ rankHO, unsigned short* __restrict__ rankBI,
                       int Eho, int Ebi) {
    int i = blockIdx.x * blockDim.x + threadIdx.x;
    int stride = gridDim.x * blockDim.x;
    int E = Eho > Ebi ? Eho : Ebi;
    for (; i < E; i += stride) {
        if (i < Eho) {
            int d = hd[i];
            unsigned long long add =
                (1ULL << 40) | (unsigned long long)(unsigned int)(hw[i] * FXSCALE + 0.5f);
            unsigned long long old = atomicAdd(&packed[d], add);
            rankHO[i] = (unsigned short)(old >> 40);
        }
        if (i < Ebi) {
            rankBI[i] = (unsigned short)atomicAdd(&cntBI[bd[i]], 1);
        }
    }
}

// ---------------- two-level exclusive scan ----------------
#define SCAN_BLOCK 1024

// HO variant: reads packed counters, emits exclusive scan of counts + dinv.
__global__ void k_scan_packed(const unsigned long long* __restrict__ packed,
                              int* __restrict__ out, int* __restrict__ sums,
                              float* __restrict__ dinv, int n) {
    __shared__ int tmp[SCAN_BLOCK];
    int gid = blockIdx.x * SCAN_BLOCK + threadIdx.x;
    unsigned long long p = (gid < n) ? packed[gid] : 0ULL;
    int v = (int)(p >> 40);
    tmp[threadIdx.x] = v;
    __syncthreads();
    for (int off = 1; off < SCAN_BLOCK; off <<= 1) {
        int t = (threadIdx.x >= off) ? tmp[threadIdx.x - off] : 0;
        __syncthreads();
        tmp[threadIdx.x] += t;
        __syncthreads();
    }
    if (gid < n) {
        out[gid] = tmp[threadIdx.x] - v;   // exclusive
        float deg = (float)(p & FXMASK) * (1.0f / FXSCALE);
        dinv[gid] = rsqrtf(deg + 1.0f);
    }
    if (threadIdx.x == SCAN_BLOCK - 1) sums[blockIdx.x] = tmp[threadIdx.x];
}

__global__ void k_scan_block(const int* __restrict__ in, int* __restrict__ out,
                             int* __restrict__ sums, int n) {
    __shared__ int tmp[SCAN_BLOCK];
    int gid = blockIdx.x * SCAN_BLOCK + threadIdx.x;
    int v = (gid < n) ? in[gid] : 0;
    tmp[threadIdx.x] = v;
    __syncthreads();
    for (int off = 1; off < SCAN_BLOCK; off <<= 1) {
        int t = (threadIdx.x >= off) ? tmp[threadIdx.x - off] : 0;
        __syncthreads();
        tmp[threadIdx.x] += t;
        __syncthreads();
    }
    if (gid < n) out[gid] = tmp[threadIdx.x] - v;
    if (threadIdx.x == SCAN_BLOCK - 1) sums[blockIdx.x] = tmp[threadIdx.x];
}

__global__ void k_scan_sums(int* __restrict__ sums, int nb) {
    __shared__ int tmp[SCAN_BLOCK];
    int v = (threadIdx.x < nb) ? sums[threadIdx.x] : 0;
    tmp[threadIdx.x] = v;
    __syncthreads();
    for (int off = 1; off < SCAN_BLOCK; off <<= 1) {
        int t = (threadIdx.x >= off) ? tmp[threadIdx.x - off] : 0;
        __syncthreads();
        tmp[threadIdx.x] += t;
        __syncthreads();
    }
    if (threadIdx.x < nb) sums[threadIdx.x] = tmp[threadIdx.x] - v;
}

__global__ void k_scan_add(int* __restrict__ out, const int* __restrict__ sums,
                           int n, int total) {
    int gid = blockIdx.x * SCAN_BLOCK + threadIdx.x;
    if (gid < n) out[gid] += sums[blockIdx.x];
    if (gid == 0) out[n] = total;
}

// ---------------- pass 2: atomic-free CSR fill ----------------

__global__ void k_fill(const int* __restrict__ hs, const int* __restrict__ hd,
                       const float* __restrict__ hw, const unsigned short* __restrict__ rankHO,
                       const float* __restrict__ dinv, const int* __restrict__ rsho,
                       int2* __restrict__ pairs,
                       const int* __restrict__ bs, const int* __restrict__ bd,
                       const unsigned short* __restrict__ rankBI, const int* __restrict__ rsbi,
                       int* __restrict__ srcbi, int Eho, int Ebi) {
    int i = blockIdx.x * blockDim.x + threadIdx.x;
    int stride = gridDim.x * blockDim.x;
    int E = Eho > Ebi ? Eho : Ebi;
    for (; i < E; i += stride) {
        if (i < Eho) {
            int d = hd[i], s = hs[i];
            pairs[rsho[d] + rankHO[i]] = make_int2(s, __float_as_int(dinv[s] * hw[i]));
        }
        if (i < Ebi) {
            int d = bd[i];
            srcbi[rsbi[d] + rankBI[i]] = bs[i];
        }
    }
}

// ---------------- A = x @ W220 : LDS-staged, coalesced ----------------

__global__ __launch_bounds__(128) void k_xw60(const float* __restrict__ x,
                                              const float* __restrict__ W,
                                              float* __restrict__ y, int N) {
    __shared__ float sx[128 * 61];     // pad 61: odd stride -> conflict-free reads
    __shared__ float sW[60 * 16];
    for (int t = threadIdx.x; t < 960; t += 128) sW[t] = W[t];
    int base = blockIdx.x * 128;
    int rows = N - base; if (rows > 128) rows = 128;
    const float4* xg = (const float4*)(x + (size_t)base * 60);
    int nf4 = rows * 15;               // 60 floats = 15 aligned float4 per row
    for (int j = threadIdx.x; j < nf4; j += 128) {
        float4 v = xg[j];
        int r = j / 15, k4 = j % 15;
        float* dst = &sx[r * 61 + k4 * 4];
        dst[0] = v.x; dst[1] = v.y; dst[2] = v.z; dst[3] = v.w;
    }
    __syncthreads();
    int t = threadIdx.x;
    if (t < rows) {
        const float* xr = &sx[t * 61];
        float acc[16];
        #pragma unroll
        for (int o = 0; o < 16; o++) acc[o] = 0.0f;
        #pragma unroll
        for (int k = 0; k < 60; k++) {
            float xv = xr[k];
            #pragma unroll
            for (int o = 0; o < 16; o++) acc[o] += xv * sW[k * 16 + o];
        }
        float4* yr = (float4*)(y + (size_t)(base + t) * 16);
        yr[0] = make_float4(acc[0], acc[1], acc[2], acc[3]);
        yr[1] = make_float4(acc[4], acc[5], acc[6], acc[7]);
        yr[2] = make_float4(acc[8], acc[9], acc[10], acc[11]);
        yr[3] = make_float4(acc[12], acc[13], acc[14], acc[15]);
    }
}

// ---------------- layer-1 gather ----------------

__global__ void k_gather1(const int2* __restrict__ pairs, const int* __restrict__ rs,
                          const float* __restrict__ dinv, const float* __restrict__ A,
                          const float* __restrict__ b, float* __restrict__ B, int N) {
    int t = blockIdx.x * blockDim.x + threadIdx.x;
    int node = t >> 4, ln = t & 15;
    if (node >= N) return;
    int beg = rs[node], end = rs[node + 1];
    float acc = 0.0f;
    for (int k = beg; k < end; k++) {
        int2 p = pairs[k];
        acc += __int_as_float(p.y) * A[(size_t)p.x * 16 + ln];
    }
    float di = dinv[node];
    float v = fmaf(di, acc, fmaf(A[(size_t)node * 16 + ln], di * di, b[ln]));
    B[(size_t)node * 16 + ln] = elu_f(v);
}

// ---------------- layer-2 gather fused with W221 + lin1 ----------------

__global__ void k_gather2(const int2* __restrict__ pairs, const int* __restrict__ rs,
                          const float* __restrict__ dinv, const float* __restrict__ B,
                          const float* __restrict__ W221, const float* __restrict__ b221,
                          const float* __restrict__ L1w, const float* __restrict__ L1b,
                          float* __restrict__ M, int N) {
    __shared__ float sW[16 * 32];
    __shared__ float sb2[32];
    __shared__ float sL[32 * 32];
    __shared__ float sLb[32];
    for (int t = threadIdx.x; t < 512; t += blockDim.x) sW[t] = W221[t];
    for (int t = threadIdx.x; t < 1024; t += blockDim.x) sL[t] = L1w[t];
    if (threadIdx.x < 32) { sb2[threadIdx.x] = b221[threadIdx.x]; sLb[threadIdx.x] = L1b[threadIdx.x]; }
    __syncthreads();
    int t = blockIdx.x * blockDim.x + threadIdx.x;
    int node = t >> 4, ln = t & 15;
    if (node >= N) return;
    int beg = rs[node], end = rs[node + 1];
    float acc = 0.0f;
    for (int k = beg; k < end; k++) {
        int2 p = pairs[k];
        acc += __int_as_float(p.y) * B[(size_t)p.x * 16 + ln];
    }
    float di = dinv[node];
    float agg = fmaf(di, acc, B[(size_t)node * 16 + ln] * di * di);
    float h2a = sb2[ln], h2b = sb2[ln + 16];
    #pragma unroll
    for (int k = 0; k < 16; k++) {
        float ak = __shfl(agg, k, 16);
        h2a += ak * sW[k * 32 + ln];
        h2b += ak * sW[k * 32 + ln + 16];
    }
    h2a = elu_f(h2a); h2b = elu_f(h2b);
    float m0 = sLb[ln], m1 = sLb[ln + 16];
    #pragma unroll
    for (int k = 0; k < 16; k++) {
        float a0 = __shfl(h2a, k, 16);
        float a1 = __shfl(h2b, k, 16);
        m0 += a0 * sL[k * 32 + ln]        + a1 * sL[(k + 16) * 32 + ln];
        m1 += a0 * sL[k * 32 + ln + 16]   + a1 * sL[(k + 16) * 32 + ln + 16];
    }
    float* mr = M + (size_t)node * 32;
    mr[ln] = m0; mr[ln + 16] = m1;
}

// ---------------- bipartite gather fused with MLP head ----------------

__global__ void k_bi_mlp(const int* __restrict__ srcs, const int* __restrict__ rs,
                         const float* __restrict__ M, const float* __restrict__ mw,
                         const float* __restrict__ mb, float* __restrict__ out, int N) {
    __shared__ float sW[32 * 10];
    __shared__ float sb[10];
    for (int t = threadIdx.x; t < 320; t += blockDim.x) sW[t] = mw[t];
    if (threadIdx.x < 10) sb[threadIdx.x] = mb[threadIdx.x];
    __syncthreads();
    int t = blockIdx.x * blockDim.x + threadIdx.x;
    int node = t >> 5, ln = t & 31;
    if (node >= N) return;
    int beg = rs[node], end = rs[node + 1];
    float acc = 0.0f;
    for (int k = beg; k < end; k++)
        acc += M[(size_t)srcs[k] * 32 + ln];
    float e = elu_f(acc);
    int lw = ln < 10 ? ln : 0;
    float o = ln < 10 ? sb[ln] : 0.0f;
    #pragma unroll
    for (int k = 0; k < 32; k++) {
        float ak = __shfl(e, k, 32);
        o += ak * sW[k * 10 + lw];
    }
    if (ln < 10) out[(size_t)node * 10 + ln] = o;
}

// ---------------- launch ----------------

extern "C" void kernel_launch(void* const* d_in, const int* in_sizes, int n_in,
                              void* d_out, int out_size, void* d_ws, size_t ws_size,
                              hipStream_t stream) {
    const float* x_ho   = (const float*)d_in[0];
    const int*   ho_src = (const int*)d_in[2];
    const int*   ho_dst = (const int*)d_in[3];
    const float* ho_w   = (const float*)d_in[4];
    const int*   bi_src = (const int*)d_in[8];
    const int*   bi_dst = (const int*)d_in[9];
    const float* W220   = (const float*)d_in[12];
    const float* b220   = (const float*)d_in[13];
    const float* W221   = (const float*)d_in[14];
    const float* b221   = (const float*)d_in[15];
    const float* lin1_w = (const float*)d_in[20];
    const float* lin1_b = (const float*)d_in[21];
    const float* mlp_w  = (const float*)d_in[24];
    const float* mlp_b  = (const float*)d_in[25];

    const int NHO = in_sizes[0] / 60;
    const int EHO = in_sizes[2];
    const int EBI = in_sizes[8];
    const int NFO = out_size / 10;
    float* out = (float*)d_out;

    // ---- workspace layout (4-byte words); 8B-aligned entries first ----
    size_t off = 0;
    float* ws = (float*)d_ws;
    unsigned long long* packed = (unsigned long long*)(ws + off); off += (size_t)2 * NHO;
    int2*  pairs = (int2*)(ws + off); off += (size_t)EHO * 2;
    float* dinv  = ws + off; off += NHO;
    float* A     = ws + off; off += (size_t)NHO * 32;    // xw1 (16 used); M overlays
    float* M     = A;
    float* B     = ws + off; off += (size_t)NHO * 16;
    int*   rs_ho = (int*)(ws + off); off += NHO + 1;
    int*   rs_bi = (int*)(ws + off); off += NFO + 1;
    int*   srcbi = (int*)(ws + off); off += EBI;
    int*   cntBI = (int*)(ws + off); off += NFO;
    unsigned short* rankHO = (unsigned short*)(ws + off); off += (EHO + 1) / 2;
    unsigned short* rankBI = (unsigned short*)(ws + off); off += (EBI + 1) / 2;
    int*   bsums = (int*)(ws + off); off += SCAN_BLOCK;

    const int BLK = 256;
    auto blocks = [&](long long n) {
        long long b = (n + BLK - 1) / BLK;
        return (int)(b > 4096 ? 4096 : b);
    };
    const int nbHO = (NHO + SCAN_BLOCK - 1) / SCAN_BLOCK;
    const int nbBI = (NFO + SCAN_BLOCK - 1) / SCAN_BLOCK;
    const int Emax = EHO > EBI ? EHO : EBI;

    // zero the atomic accumulators
    hipMemsetAsync(packed, 0, (size_t)NHO * 8, stream);
    hipMemsetAsync(cntBI, 0, (size_t)NFO * 4, stream);

    // pass 1: packed histogram + per-edge rank capture
    k_hist<<<blocks(Emax), BLK, 0, stream>>>(ho_dst, ho_w, bi_dst,
                                             packed, cntBI, rankHO, rankBI, EHO, EBI);

    // scans (HO scan also unpacks deg -> dinv)
    k_scan_packed<<<nbHO, SCAN_BLOCK, 0, stream>>>(packed, rs_ho, bsums, dinv, NHO);
    k_scan_sums<<<1, SCAN_BLOCK, 0, stream>>>(bsums, nbHO);
    k_scan_add<<<nbHO, SCAN_BLOCK, 0, stream>>>(rs_ho, bsums, NHO, EHO);
    k_scan_block<<<nbBI, SCAN_BLOCK, 0, stream>>>(cntBI, rs_bi, bsums, NFO);
    k_scan_sums<<<1, SCAN_BLOCK, 0, stream>>>(bsums, nbBI);
    k_scan_add<<<nbBI, SCAN_BLOCK, 0, stream>>>(rs_bi, bsums, NFO, EBI);

    // pass 2: atomic-free CSR fill
    k_fill<<<blocks(Emax), BLK, 0, stream>>>(ho_src, ho_dst, ho_w, rankHO, dinv, rs_ho, pairs,
                                             bi_src, bi_dst, rankBI, rs_bi, srcbi, EHO, EBI);

    // A = x @ W220
    k_xw60<<<(NHO + 127) / 128, 128, 0, stream>>>(x_ho, W220, A, NHO);

    // B = elu(gcn1)
    {
        long long t = (long long)NHO * 16;
        k_gather1<<<(int)((t + BLK - 1) / BLK), BLK, 0, stream>>>(
            pairs, rs_ho, dinv, A, b220, B, NHO);
    }
    // M = (elu(gcn2)) @ lin1 + lin1_b
    {
        long long t = (long long)NHO * 16;
        k_gather2<<<(int)((t + BLK - 1) / BLK), BLK, 0, stream>>>(
            pairs, rs_ho, dinv, B, W221, b221, lin1_w, lin1_b, M, NHO);
    }
    // out = elu(bipartite sum of M) @ mlp_w + mlp_b
    {
        long long t = (long long)NFO * 32;
        k_bi_mlp<<<(int)((t + BLK - 1) / BLK), BLK, 0, stream>>>(
            srcbi, rs_bi, M, mlp_w, mlp_b, out, NFO);
    }
}

// Round 5
// 668.392 us; speedup vs baseline: 18.7614x; 1.2526x over previous
//
#include <hip/hip_runtime.h>
#include <math.h>

#define SCAN_BLOCK 1024
#define FXSCALE 67108864.0f              // 2^26 fixed-point scale for weight sums
#define FXMASK  ((1ULL << 40) - 1)

static __device__ __forceinline__ float elu_f(float x) {
    return x > 0.0f ? x : expm1f(x);
}

// ---------------- fused: packed histogram + rank capture  ||  A = x @ W220 ----------------
// Blocks [0, xwBlocks) compute the dense matvec (LDS-staged, coalesced float4).
// Blocks [xwBlocks, ...) do one 64-bit atomic per HO edge (count<<40 | fx weight sum,
// return value = within-node rank) and one 32-bit atomic per BI edge.

__global__ __launch_bounds__(256) void k_hist_xw(
    const int* __restrict__ hd, const float* __restrict__ hw, const int* __restrict__ bd,
    unsigned long long* __restrict__ packed, int* __restrict__ cntBI,
    unsigned short* __restrict__ rankHO, unsigned short* __restrict__ rankBI,
    int Eho, int Ebi,
    const float* __restrict__ x, const float* __restrict__ W, float* __restrict__ A,
    int N, int xwBlocks)
{
    __shared__ float sx[128 * 61];       // pad 61: conflict-free LDS reads
    __shared__ float sW[960];
    if ((int)blockIdx.x < xwBlocks) {
        for (int t = threadIdx.x; t < 960; t += 256) sW[t] = W[t];
        int base = blockIdx.x * 128;
        int rows = N - base; if (rows > 128) rows = 128;
        const float4* xg = (const float4*)(x + (size_t)base * 60);
        int nf4 = rows * 15;             // 60 floats = 15 aligned float4 per row
        for (int j = threadIdx.x; j < nf4; j += 256) {
            float4 v = xg[j];
            int r = j / 15, k4 = j - r * 15;
            float* dst = &sx[r * 61 + k4 * 4];
            dst[0] = v.x; dst[1] = v.y; dst[2] = v.z; dst[3] = v.w;
        }
        __syncthreads();
        int t = threadIdx.x;
        if (t < rows) {
            const float* xr = &sx[t * 61];
            float acc[16];
            #pragma unroll
            for (int o = 0; o < 16; o++) acc[o] = 0.0f;
            #pragma unroll
            for (int k = 0; k < 60; k++) {
                float xv = xr[k];
                #pragma unroll
                for (int o = 0; o < 16; o++) acc[o] = fmaf(xv, sW[k * 16 + o], acc[o]);
            }
            float4* yr = (float4*)(A + (size_t)(base + t) * 16);
            yr[0] = make_float4(acc[0], acc[1], acc[2], acc[3]);
            yr[1] = make_float4(acc[4], acc[5], acc[6], acc[7]);
            yr[2] = make_float4(acc[8], acc[9], acc[10], acc[11]);
            yr[3] = make_float4(acc[12], acc[13], acc[14], acc[15]);
        }
        return;
    }
    int i = (blockIdx.x - xwBlocks) * 256 + threadIdx.x;
    int stride = ((int)gridDim.x - xwBlocks) * 256;
    int E = Eho > Ebi ? Eho : Ebi;
    for (; i < E; i += stride) {
        if (i < Eho) {
            int d = hd[i];
            unsigned long long add =
                (1ULL << 40) | (unsigned long long)(unsigned int)(hw[i] * FXSCALE + 0.5f);
            unsigned long long old = atomicAdd(&packed[d], add);
            rankHO[i] = (unsigned short)(old >> 40);
        }
        if (i < Ebi) rankBI[i] = (unsigned short)atomicAdd(&cntBI[bd[i]], 1);
    }
}

// ---------------- fused two-level exclusive scans (HO packed + BI) ----------------

__global__ void k_scan_fused(const unsigned long long* __restrict__ packed,
                             int* __restrict__ rsHO, float* __restrict__ dinv,
                             int nHO, int nbHO,
                             const int* __restrict__ cntBI, int* __restrict__ rsBI, int nBI,
                             int* __restrict__ sumsHO, int* __restrict__ sumsBI) {
    __shared__ int tmp[SCAN_BLOCK];
    int b = blockIdx.x;
    if (b < nbHO) {
        int gid = b * SCAN_BLOCK + threadIdx.x;
        unsigned long long p = (gid < nHO) ? packed[gid] : 0ULL;
        int v = (int)(p >> 40);
        tmp[threadIdx.x] = v;
        __syncthreads();
        for (int off = 1; off < SCAN_BLOCK; off <<= 1) {
            int t = (threadIdx.x >= off) ? tmp[threadIdx.x - off] : 0;
            __syncthreads();
            tmp[threadIdx.x] += t;
            __syncthreads();
        }
        if (gid < nHO) {
            rsHO[gid] = tmp[threadIdx.x] - v;
            float deg = (float)(p & FXMASK) * (1.0f / FXSCALE);
            dinv[gid] = rsqrtf(deg + 1.0f);
        }
        if (threadIdx.x == SCAN_BLOCK - 1) sumsHO[b] = tmp[threadIdx.x];
    } else {
        int b2 = b - nbHO;
        int gid = b2 * SCAN_BLOCK + threadIdx.x;
        int v = (gid < nBI) ? cntBI[gid] : 0;
        tmp[threadIdx.x] = v;
        __syncthreads();
        for (int off = 1; off < SCAN_BLOCK; off <<= 1) {
            int t = (threadIdx.x >= off) ? tmp[threadIdx.x - off] : 0;
            __syncthreads();
            tmp[threadIdx.x] += t;
            __syncthreads();
        }
        if (gid < nBI) rsBI[gid] = tmp[threadIdx.x] - v;
        if (threadIdx.x == SCAN_BLOCK - 1) sumsBI[b2] = tmp[threadIdx.x];
    }
}

__global__ void k_scan_sums2(int* __restrict__ sumsHO, int nbHO,
                             int* __restrict__ sumsBI, int nbBI) {
    __shared__ int tmp[SCAN_BLOCK];
    int* s = (blockIdx.x == 0) ? sumsHO : sumsBI;
    int nb  = (blockIdx.x == 0) ? nbHO : nbBI;
    int v = (threadIdx.x < nb) ? s[threadIdx.x] : 0;
    tmp[threadIdx.x] = v;
    __syncthreads();
    for (int off = 1; off < SCAN_BLOCK; off <<= 1) {
        int t = (threadIdx.x >= off) ? tmp[threadIdx.x - off] : 0;
        __syncthreads();
        tmp[threadIdx.x] += t;
        __syncthreads();
    }
    if (threadIdx.x < nb) s[threadIdx.x] = tmp[threadIdx.x] - v;
}

__global__ void k_scan_add2(int* __restrict__ rsHO, const int* __restrict__ sumsHO,
                            int nHO, int totHO, int nbHO,
                            int* __restrict__ rsBI, const int* __restrict__ sumsBI,
                            int nBI, int totBI) {
    int b = blockIdx.x;
    if (b < nbHO) {
        int gid = b * SCAN_BLOCK + threadIdx.x;
        if (gid < nHO) rsHO[gid] += sumsHO[b];
        if (gid == 0) rsHO[nHO] = totHO;
    } else {
        int b2 = b - nbHO;
        int gid = b2 * SCAN_BLOCK + threadIdx.x;
        if (gid < nBI) rsBI[gid] += sumsBI[b2];
        if (gid == 0) rsBI[nBI] = totBI;
    }
}

// ---------------- atomic-free CSR fill ----------------

__global__ void k_fill(const int* __restrict__ hs, const int* __restrict__ hd,
                       const float* __restrict__ hw, const unsigned short* __restrict__ rankHO,
                       const float* __restrict__ dinv, const int* __restrict__ rsho,
                       int2* __restrict__ pairs,
                       const int* __restrict__ bs, const int* __restrict__ bd,
                       const unsigned short* __restrict__ rankBI, const int* __restrict__ rsbi,
                       int* __restrict__ srcbi, int Eho, int Ebi) {
    int i = blockIdx.x * blockDim.x + threadIdx.x;
    int stride = gridDim.x * blockDim.x;
    int E = Eho > Ebi ? Eho : Ebi;
    for (; i < E; i += stride) {
        if (i < Eho) {
            int d = hd[i], s = hs[i];
            pairs[rsho[d] + rankHO[i]] = make_int2(s, __float_as_int(dinv[s] * hw[i]));
        }
        if (i < Ebi) {
            int d = bd[i];
            srcbi[rsbi[d] + rankBI[i]] = bs[i];
        }
    }
}

// edge-dot macro for the 16-lane gathers
#define EDGE_FMA(SRCTAB, J) \
    acc = fmaf(__int_as_float(__shfl(p.y, (J), 16)), \
               SRCTAB[(size_t)__shfl(p.x, (J), 16) * 16 + ln], acc);

// ---------------- layer-1 gather: B = elu(dinv*sum + A*dinv^2 + b220) ----------------
// 16 lanes/node; edges loaded 16-wide coalesced, broadcast via shfl, unrolled for MLP.

__global__ void k_gather1(const int2* __restrict__ pairs, const int* __restrict__ rs,
                          const float* __restrict__ dinv, const float* __restrict__ A,
                          const float* __restrict__ b, float* __restrict__ B, int N) {
    int t = blockIdx.x * blockDim.x + threadIdx.x;
    int node = t >> 4, ln = t & 15;
    if (node >= N) return;
    int beg = rs[node], end = rs[node + 1];
    float acc = 0.0f;
    for (int k = beg; k < end; k += 16) {
        int take = end - k; if (take > 16) take = 16;
        int2 p = pairs[k + (ln < take ? ln : take - 1)];
        if (take == 16) {
            #pragma unroll
            for (int j = 0; j < 16; j++) { EDGE_FMA(A, j) }
        } else {
            int j = 0;
            if (take >= 8) {
                #pragma unroll
                for (int jj = 0; jj < 8; jj++) { EDGE_FMA(A, jj) }
                j = 8;
            }
            if (take - j >= 4) {
                #pragma unroll
                for (int jj = 0; jj < 4; jj++) { EDGE_FMA(A, j + jj) }
                j += 4;
            }
            for (; j < take; j++) { EDGE_FMA(A, j) }
        }
    }
    float di = dinv[node];
    float v = fmaf(di, acc, fmaf(A[(size_t)node * 16 + ln], di * di, b[ln]));
    B[(size_t)node * 16 + ln] = elu_f(v);
}

// ---------------- layer-2 gather fused with W221 + lin1 (aggregate-then-transform) ----------------

__global__ void k_gather2(const int2* __restrict__ pairs, const int* __restrict__ rs,
                          const float* __restrict__ dinv, const float* __restrict__ B,
                          const float* __restrict__ W221, const float* __restrict__ b221,
                          const float* __restrict__ L1w, const float* __restrict__ L1b,
                          float* __restrict__ M, int N) {
    __shared__ float sW[16 * 32];
    __shared__ float sb2[32];
    __shared__ float sL[32 * 32];
    __shared__ float sLb[32];
    for (int t = threadIdx.x; t < 512; t += blockDim.x) sW[t] = W221[t];
    for (int t = threadIdx.x; t < 1024; t += blockDim.x) sL[t] = L1w[t];
    if (threadIdx.x < 32) { sb2[threadIdx.x] = b221[threadIdx.x]; sLb[threadIdx.x] = L1b[threadIdx.x]; }
    __syncthreads();
    int t = blockIdx.x * blockDim.x + threadIdx.x;
    int node = t >> 4, ln = t & 15;
    if (node >= N) return;
    int beg = rs[node], end = rs[node + 1];
    float acc = 0.0f;
    for (int k = beg; k < end; k += 16) {
        int take = end - k; if (take > 16) take = 16;
        int2 p = pairs[k + (ln < take ? ln : take - 1)];
        if (take == 16) {
            #pragma unroll
            for (int j = 0; j < 16; j++) { EDGE_FMA(B, j) }
        } else {
            int j = 0;
            if (take >= 8) {
                #pragma unroll
                for (int jj = 0; jj < 8; jj++) { EDGE_FMA(B, jj) }
                j = 8;
            }
            if (take - j >= 4) {
                #pragma unroll
                for (int jj = 0; jj < 4; jj++) { EDGE_FMA(B, j + jj) }
                j += 4;
            }
            for (; j < take; j++) { EDGE_FMA(B, j) }
        }
    }
    float di = dinv[node];
    float agg = fmaf(di, acc, B[(size_t)node * 16 + ln] * di * di);
    float h2a = sb2[ln], h2b = sb2[ln + 16];
    #pragma unroll
    for (int k = 0; k < 16; k++) {
        float ak = __shfl(agg, k, 16);
        h2a += ak * sW[k * 32 + ln];
        h2b += ak * sW[k * 32 + ln + 16];
    }
    h2a = elu_f(h2a); h2b = elu_f(h2b);
    float m0 = sLb[ln], m1 = sLb[ln + 16];
    #pragma unroll
    for (int k = 0; k < 16; k++) {
        float a0 = __shfl(h2a, k, 16);
        float a1 = __shfl(h2b, k, 16);
        m0 += a0 * sL[k * 32 + ln]        + a1 * sL[(k + 16) * 32 + ln];
        m1 += a0 * sL[k * 32 + ln + 16]   + a1 * sL[(k + 16) * 32 + ln + 16];
    }
    float* mr = M + (size_t)node * 32;
    mr[ln] = m0; mr[ln + 16] = m1;
}

// ---------------- bipartite gather fused with MLP head ----------------
// 32 lanes/node; srcs loaded 32-wide coalesced + shfl broadcast.

__global__ void k_bi_mlp(const int* __restrict__ srcs, const int* __restrict__ rs,
                         const float* __restrict__ M, const float* __restrict__ mw,
                         const float* __restrict__ mb, float* __restrict__ out, int N) {
    __shared__ float sW[32 * 10];
    __shared__ float sb[10];
    for (int t = threadIdx.x; t < 320; t += blockDim.x) sW[t] = mw[t];
    if (threadIdx.x < 10) sb[threadIdx.x] = mb[threadIdx.x];
    __syncthreads();
    int t = blockIdx.x * blockDim.x + threadIdx.x;
    int node = t >> 5, ln = t & 31;
    if (node >= N) return;
    int beg = rs[node], end = rs[node + 1];
    float acc = 0.0f;
    for (int k = beg; k < end; k += 32) {
        int take = end - k; if (take > 32) take = 32;
        int ms = srcs[k + (ln < take ? ln : take - 1)];
        if (take == 32) {
            #pragma unroll
            for (int j = 0; j < 32; j++)
                acc += M[(size_t)__shfl(ms, j, 32) * 32 + ln];
        } else {
            int j = 0;
            if (take >= 16) {
                #pragma unroll
                for (int jj = 0; jj < 16; jj++)
                    acc += M[(size_t)__shfl(ms, jj, 32) * 32 + ln];
                j = 16;
            }
            if (take - j >= 8) {
                #pragma unroll
                for (int jj = 0; jj < 8; jj++)
                    acc += M[(size_t)__shfl(ms, j + jj, 32) * 32 + ln];
                j += 8;
            }
            if (take - j >= 4) {
                #pragma unroll
                for (int jj = 0; jj < 4; jj++)
                    acc += M[(size_t)__shfl(ms, j + jj, 32) * 32 + ln];
                j += 4;
            }
            for (; j < take; j++)
                acc += M[(size_t)__shfl(ms, j, 32) * 32 + ln];
        }
    }
    float e = elu_f(acc);
    int lw = ln < 10 ? ln : 0;
    float o = ln < 10 ? sb[ln] : 0.0f;
    #pragma unroll
    for (int k = 0; k < 32; k++) {
        float ak = __shfl(e, k, 32);
        o += ak * sW[k * 10 + lw];
    }
    if (ln < 10) out[(size_t)node * 10 + ln] = o;
}

// ---------------- launch ----------------

extern "C" void kernel_launch(void* const* d_in, const int* in_sizes, int n_in,
                              void* d_out, int out_size, void* d_ws, size_t ws_size,
                              hipStream_t stream) {
    const float* x_ho   = (const float*)d_in[0];
    const int*   ho_src = (const int*)d_in[2];
    const int*   ho_dst = (const int*)d_in[3];
    const float* ho_w   = (const float*)d_in[4];
    const int*   bi_src = (const int*)d_in[8];
    const int*   bi_dst = (const int*)d_in[9];
    const float* W220   = (const float*)d_in[12];
    const float* b220   = (const float*)d_in[13];
    const float* W221   = (const float*)d_in[14];
    const float* b221   = (const float*)d_in[15];
    const float* lin1_w = (const float*)d_in[20];
    const float* lin1_b = (const float*)d_in[21];
    const float* mlp_w  = (const float*)d_in[24];
    const float* mlp_b  = (const float*)d_in[25];

    const int NHO = in_sizes[0] / 60;
    const int EHO = in_sizes[2];
    const int EBI = in_sizes[8];
    const int NFO = out_size / 10;
    float* out = (float*)d_out;

    // ---- workspace layout (4-byte words); packed+cntBI contiguous for one memset ----
    size_t off = 0;
    float* ws = (float*)d_ws;
    unsigned long long* packed = (unsigned long long*)(ws + off); off += (size_t)2 * NHO;
    int*   cntBI = (int*)(ws + off); off += NFO;
    off = (off + 1) & ~(size_t)1;                        // 8B align
    int2*  pairs = (int2*)(ws + off); off += (size_t)EHO * 2;
    float* dinv  = ws + off; off += NHO;
    float* A     = ws + off; off += (size_t)NHO * 32;    // xw1 (16 used); M overlays
    float* M     = A;
    float* B     = ws + off; off += (size_t)NHO * 16;
    int*   rs_ho = (int*)(ws + off); off += NHO + 1;
    int*   rs_bi = (int*)(ws + off); off += NFO + 1;
    int*   srcbi = (int*)(ws + off); off += EBI;
    unsigned short* rankHO = (unsigned short*)(ws + off); off += (EHO + 1) / 2;
    unsigned short* rankBI = (unsigned short*)(ws + off); off += (EBI + 1) / 2;
    int*   sumsHO = (int*)(ws + off); off += SCAN_BLOCK;
    int*   sumsBI = (int*)(ws + off); off += SCAN_BLOCK;

    const int BLK = 256;
    auto blocks = [&](long long n) {
        long long b = (n + BLK - 1) / BLK;
        return (int)(b > 4096 ? 4096 : b);
    };
    const int nbHO = (NHO + SCAN_BLOCK - 1) / SCAN_BLOCK;
    const int nbBI = (NFO + SCAN_BLOCK - 1) / SCAN_BLOCK;
    const int Emax = EHO > EBI ? EHO : EBI;
    const int xwBlocks = (NHO + 127) / 128;

    // zero the atomic accumulators (one contiguous region)
    hipMemsetAsync(packed, 0, ((size_t)2 * NHO + NFO) * 4, stream);

    // fused: histogram+rank atomics || x @ W220
    k_hist_xw<<<xwBlocks + blocks(Emax), BLK, 0, stream>>>(
        ho_dst, ho_w, bi_dst, packed, cntBI, rankHO, rankBI, EHO, EBI,
        x_ho, W220, A, NHO, xwBlocks);

    // fused scans (HO unpacks deg -> dinv too)
    k_scan_fused<<<nbHO + nbBI, SCAN_BLOCK, 0, stream>>>(
        packed, rs_ho, dinv, NHO, nbHO, cntBI, rs_bi, NFO, sumsHO, sumsBI);
    k_scan_sums2<<<2, SCAN_BLOCK, 0, stream>>>(sumsHO, nbHO, sumsBI, nbBI);
    k_scan_add2<<<nbHO + nbBI, SCAN_BLOCK, 0, stream>>>(
        rs_ho, sumsHO, NHO, EHO, nbHO, rs_bi, sumsBI, NFO, EBI);

    // atomic-free CSR fill (both graphs)
    k_fill<<<blocks(Emax), BLK, 0, stream>>>(ho_src, ho_dst, ho_w, rankHO, dinv, rs_ho, pairs,
                                             bi_src, bi_dst, rankBI, rs_bi, srcbi, EHO, EBI);

    // B = elu(gcn1)
    {
        long long t = (long long)NHO * 16;
        k_gather1<<<(int)((t + BLK - 1) / BLK), BLK, 0, stream>>>(
            pairs, rs_ho, dinv, A, b220, B, NHO);
    }
    // M = (elu(gcn2)) @ lin1 + lin1_b
    {
        long long t = (long long)NHO * 16;
        k_gather2<<<(int)((t + BLK - 1) / BLK), BLK, 0, stream>>>(
            pairs, rs_ho, dinv, B, W221, b221, lin1_w, lin1_b, M, NHO);
    }
    // out = elu(bipartite sum of M) @ mlp_w + mlp_b
    {
        long long t = (long long)NFO * 32;
        k_bi_mlp<<<(int)((t + BLK - 1) / BLK), BLK, 0, stream>>>(
            srcbi, rs_bi, M, mlp_w, mlp_b, out, NFO);
    }
}

// Round 6
// 509.443 us; speedup vs baseline: 24.6151x; 1.3120x over previous
//
#include <hip/hip_runtime.h>
#include <math.h>

#define SCAN_BLOCK 1024
#define BK_BITS 9
#define BKSZ 512                 // nodes per bucket
#define CH 16384                 // HO edges per chunk (pass A/C must match)
#define FXS 33554432.0f          // 2^25 fixed-point scale for per-bucket deg sums

static __device__ __forceinline__ float elu_f(float x) {
    return x > 0.0f ? x : expm1f(x);
}

// ---------------- pass A ----------------
// blocks [0, nChunks): per-chunk LDS bucket histogram of HO dst (no global atomics)
// blocks [nChunks, nChunks+biB): BI rank atomics (proven path)
// blocks [nChunks+biB, ...): A = x @ W220, 64-row LDS tiles

__global__ __launch_bounds__(256) void k_passA(
    const int* __restrict__ hd, int* __restrict__ counts, int nChunks, int Eho, int NB,
    const int* __restrict__ bd, int* __restrict__ cntBI, unsigned short* __restrict__ rankBI,
    int Ebi, int biB,
    const float* __restrict__ x, const float* __restrict__ W, float* __restrict__ Axw, int N)
{
    __shared__ float smem[64 * 61 + 960];     // union: bucket hist / xw staging
    int bid = blockIdx.x;
    if (bid < nChunks) {
        unsigned* h = (unsigned*)smem;
        for (int t = threadIdx.x; t < NB; t += 256) h[t] = 0u;
        __syncthreads();
        int e0 = bid * CH;
        int e1 = e0 + CH; if (e1 > Eho) e1 = Eho;
        for (int e = e0 + threadIdx.x; e < e1; e += 256)
            atomicAdd(&h[(unsigned)hd[e] >> BK_BITS], 1u);
        __syncthreads();
        for (int t = threadIdx.x; t < NB; t += 256)
            counts[(size_t)t * nChunks + bid] = (int)h[t];
        return;
    }
    bid -= nChunks;
    if (bid < biB) {
        int i = bid * 256 + threadIdx.x;
        int stride = biB * 256;
        for (; i < Ebi; i += stride)
            rankBI[i] = (unsigned short)atomicAdd(&cntBI[bd[i]], 1);
        return;
    }
    bid -= biB;
    float* sx = smem;
    float* sW = smem + 64 * 61;
    for (int t = threadIdx.x; t < 960; t += 256) sW[t] = W[t];
    int base = bid * 64;
    int rows = N - base; if (rows > 64) rows = 64;
    const float4* xg = (const float4*)(x + (size_t)base * 60);
    int nf4 = rows * 15;
    for (int j = threadIdx.x; j < nf4; j += 256) {
        float4 v = xg[j];
        int r = j / 15, k4 = j - r * 15;
        float* dst = &sx[r * 61 + k4 * 4];
        dst[0] = v.x; dst[1] = v.y; dst[2] = v.z; dst[3] = v.w;
    }
    __syncthreads();
    int t = threadIdx.x;
    if (t < rows) {
        const float* xr = &sx[t * 61];
        float acc[16];
        #pragma unroll
        for (int o = 0; o < 16; o++) acc[o] = 0.0f;
        #pragma unroll
        for (int k = 0; k < 60; k++) {
            float xv = xr[k];
            #pragma unroll
            for (int o = 0; o < 16; o++) acc[o] = fmaf(xv, sW[k * 16 + o], acc[o]);
        }
        float4* yr = (float4*)(Axw + (size_t)(base + t) * 16);
        yr[0] = make_float4(acc[0], acc[1], acc[2], acc[3]);
        yr[1] = make_float4(acc[4], acc[5], acc[6], acc[7]);
        yr[2] = make_float4(acc[8], acc[9], acc[10], acc[11]);
        yr[3] = make_float4(acc[12], acc[13], acc[14], acc[15]);
    }
}

// ---------------- fused two-range exclusive scan ----------------

__global__ void k_scan2(const int* __restrict__ in1, int* __restrict__ out1, int n1, int nb1,
                        const int* __restrict__ in2, int* __restrict__ out2, int n2,
                        int* __restrict__ sums1, int* __restrict__ sums2) {
    __shared__ int tmp[SCAN_BLOCK];
    int b = blockIdx.x;
    const int* in; int* out; int n; int* sums; int bb;
    if (b < nb1) { in = in1; out = out1; n = n1; sums = sums1; bb = b; }
    else         { in = in2; out = out2; n = n2; sums = sums2; bb = b - nb1; }
    int gid = bb * SCAN_BLOCK + threadIdx.x;
    int v = (gid < n) ? in[gid] : 0;
    tmp[threadIdx.x] = v;
    __syncthreads();
    for (int off = 1; off < SCAN_BLOCK; off <<= 1) {
        int t = (threadIdx.x >= off) ? tmp[threadIdx.x - off] : 0;
        __syncthreads();
        tmp[threadIdx.x] += t;
        __syncthreads();
    }
    if (gid < n) out[gid] = tmp[threadIdx.x] - v;
    if (threadIdx.x == SCAN_BLOCK - 1) sums[bb] = tmp[threadIdx.x];
}

__global__ void k_scan_sums2(int* __restrict__ sums1, int nb1,
                             int* __restrict__ sums2, int nb2) {
    __shared__ int tmp[SCAN_BLOCK];
    int* s = (blockIdx.x == 0) ? sums1 : sums2;
    int nb = (blockIdx.x == 0) ? nb1 : nb2;
    int v = (threadIdx.x < nb) ? s[threadIdx.x] : 0;
    tmp[threadIdx.x] = v;
    __syncthreads();
    for (int off = 1; off < SCAN_BLOCK; off <<= 1) {
        int t = (threadIdx.x >= off) ? tmp[threadIdx.x - off] : 0;
        __syncthreads();
        tmp[threadIdx.x] += t;
        __syncthreads();
    }
    if (threadIdx.x < nb) s[threadIdx.x] = tmp[threadIdx.x] - v;
}

__global__ void k_scan_add2(int* __restrict__ out1, const int* __restrict__ sums1,
                            int n1, int tot1, int nb1,
                            int* __restrict__ out2, const int* __restrict__ sums2,
                            int n2, int tot2) {
    int b = blockIdx.x;
    if (b < nb1) {
        int gid = b * SCAN_BLOCK + threadIdx.x;
        if (gid < n1) out1[gid] += sums1[b];
        if (gid == 0) out1[n1] = tot1;
    } else {
        int b2 = b - nb1;
        int gid = b2 * SCAN_BLOCK + threadIdx.x;
        if (gid < n2) out2[gid] += sums2[b2];
        if (gid == 0) out2[n2] = tot2;
    }
}

// ---------------- pass C: bucket-ordered scatter (LDS cursors) + BI fill ----------------
// eS[pos] = (src | nodeLow<<19, w) -- src < 2^19, nodeLow 9 bits.

__global__ __launch_bounds__(256) void k_passC(
    const int* __restrict__ hs, const int* __restrict__ hd, const float* __restrict__ hw,
    const int* __restrict__ countsS, int nChunks, int NB, int Eho,
    int2* __restrict__ eS,
    const int* __restrict__ bs, const int* __restrict__ bd,
    const unsigned short* __restrict__ rankBI, const int* __restrict__ rsbi,
    int* __restrict__ srcbi, int Ebi)
{
    __shared__ int cur[1024];
    int bid = blockIdx.x;
    if (bid < nChunks) {
        for (int t = threadIdx.x; t < NB; t += 256)
            cur[t] = countsS[(size_t)t * nChunks + bid];
        __syncthreads();
        int e0 = bid * CH;
        int e1 = e0 + CH; if (e1 > Eho) e1 = Eho;
        for (int e = e0 + threadIdx.x; e < e1; e += 256) {
            int d = hd[e];
            int pos = atomicAdd(&cur[(unsigned)d >> BK_BITS], 1);
            eS[pos] = make_int2(hs[e] | ((d & (BKSZ - 1)) << 19), __float_as_int(hw[e]));
        }
        return;
    }
    bid -= nChunks;
    int i = bid * 256 + threadIdx.x;
    int stride = ((int)gridDim.x - nChunks) * 256;
    for (; i < Ebi; i += stride)
        srcbi[rsbi[bd[i]] + rankBI[i]] = bs[i];
}

// ---------------- pass D: per-bucket CSR finalize (LDS only) ----------------

__global__ __launch_bounds__(1024) void k_passD(
    const int2* __restrict__ eS, const int* __restrict__ countsS, int nChunks,
    int NB, int Eho, int NHO,
    int2* __restrict__ pairs, int* __restrict__ rs_ho, float* __restrict__ dinv)
{
    __shared__ unsigned cnt[BKSZ];
    __shared__ unsigned fx[BKSZ];
    __shared__ int sc[BKSZ];
    __shared__ int cur[BKSZ];
    int b = blockIdx.x;
    int base = countsS[(size_t)b * nChunks];
    int end  = (b == NB - 1) ? Eho : countsS[(size_t)(b + 1) * nChunks];
    int tid = threadIdx.x;
    if (tid < BKSZ) { cnt[tid] = 0u; fx[tid] = 0u; }
    __syncthreads();
    for (int e = base + tid; e < end; e += 1024) {
        int2 p = eS[e];
        int n = (unsigned)p.x >> 19;
        atomicAdd(&cnt[n], 1u);
        atomicAdd(&fx[n], (unsigned)(__int_as_float(p.y) * FXS + 0.5f));
    }
    __syncthreads();
    if (tid < BKSZ) sc[tid] = (int)cnt[tid];
    __syncthreads();
    for (int off = 1; off < BKSZ; off <<= 1) {
        int t = (tid < BKSZ && tid >= off) ? sc[tid - off] : 0;
        __syncthreads();
        if (tid < BKSZ) sc[tid] += t;
        __syncthreads();
    }
    if (tid < BKSZ) {
        int gn = b * BKSZ + tid;
        if (gn < NHO) {
            int off0 = sc[tid] - (int)cnt[tid];       // exclusive
            cur[tid] = base + off0;
            rs_ho[gn] = base + off0;
            dinv[gn] = rsqrtf((float)fx[tid] * (1.0f / FXS) + 1.0f);
        }
    }
    if (b == NB - 1 && tid == 0) rs_ho[NHO] = Eho;
    __syncthreads();
    for (int e = base + tid; e < end; e += 1024) {
        int2 p = eS[e];
        int n = (unsigned)p.x >> 19;
        int pos = atomicAdd(&cur[n], 1);
        pairs[pos] = make_int2(p.x & 0x7FFFF, p.y);
    }
}

// ---------------- pass E: fold dinv[src] into pair weights ----------------

__global__ void k_passE(int2* __restrict__ pairs, const float* __restrict__ dinv, int E) {
    int i = blockIdx.x * blockDim.x + threadIdx.x;
    int stride = gridDim.x * blockDim.x;
    for (; i < E; i += stride) {
        int2 p = pairs[i];
        pairs[i] = make_int2(p.x, __float_as_int(__int_as_float(p.y) * dinv[p.x]));
    }
}

// edge-dot macro for the 16-lane gathers
#define EDGE_FMA(SRCTAB, J) \
    acc = fmaf(__int_as_float(__shfl(p.y, (J), 16)), \
               SRCTAB[(size_t)__shfl(p.x, (J), 16) * 16 + ln], acc);

// ---------------- layer-1 gather: B = elu(dinv*sum + A*dinv^2 + b220) ----------------

__global__ void k_gather1(const int2* __restrict__ pairs, const int* __restrict__ rs,
                          const float* __restrict__ dinv, const float* __restrict__ A,
                          const float* __restrict__ b, float* __restrict__ B, int N) {
    int t = blockIdx.x * blockDim.x + threadIdx.x;
    int node = t >> 4, ln = t & 15;
    if (node >= N) return;
    int beg = rs[node], end = rs[node + 1];
    float acc = 0.0f;
    for (int k = beg; k < end; k += 16) {
        int take = end - k; if (take > 16) take = 16;
        int2 p = pairs[k + (ln < take ? ln : take - 1)];
        if (take == 16) {
            #pragma unroll
            for (int j = 0; j < 16; j++) { EDGE_FMA(A, j) }
        } else {
            int j = 0;
            if (take >= 8) {
                #pragma unroll
                for (int jj = 0; jj < 8; jj++) { EDGE_FMA(A, jj) }
                j = 8;
            }
            if (take - j >= 4) {
                #pragma unroll
                for (int jj = 0; jj < 4; jj++) { EDGE_FMA(A, j + jj) }
                j += 4;
            }
            for (; j < take; j++) { EDGE_FMA(A, j) }
        }
    }
    float di = dinv[node];
    float v = fmaf(di, acc, fmaf(A[(size_t)node * 16 + ln], di * di, b[ln]));
    B[(size_t)node * 16 + ln] = elu_f(v);
}

// ---------------- layer-2 gather fused with W221 + lin1 ----------------

__global__ void k_gather2(const int2* __restrict__ pairs, const int* __restrict__ rs,
                          const float* __restrict__ dinv, const float* __restrict__ B,
                          const float* __restrict__ W221, const float* __restrict__ b221,
                          const float* __restrict__ L1w, const float* __restrict__ L1b,
                          float* __restrict__ M, int N) {
    __shared__ float sW[16 * 32];
    __shared__ float sb2[32];
    __shared__ float sL[32 * 32];
    __shared__ float sLb[32];
    for (int t = threadIdx.x; t < 512; t += blockDim.x) sW[t] = W221[t];
    for (int t = threadIdx.x; t < 1024; t += blockDim.x) sL[t] = L1w[t];
    if (threadIdx.x < 32) { sb2[threadIdx.x] = b221[threadIdx.x]; sLb[threadIdx.x] = L1b[threadIdx.x]; }
    __syncthreads();
    int t = blockIdx.x * blockDim.x + threadIdx.x;
    int node = t >> 4, ln = t & 15;
    if (node >= N) return;
    int beg = rs[node], end = rs[node + 1];
    float acc = 0.0f;
    for (int k = beg; k < end; k += 16) {
        int take = end - k; if (take > 16) take = 16;
        int2 p = pairs[k + (ln < take ? ln : take - 1)];
        if (take == 16) {
            #pragma unroll
            for (int j = 0; j < 16; j++) { EDGE_FMA(B, j) }
        } else {
            int j = 0;
            if (take >= 8) {
                #pragma unroll
                for (int jj = 0; jj < 8; jj++) { EDGE_FMA(B, jj) }
                j = 8;
            }
            if (take - j >= 4) {
                #pragma unroll
                for (int jj = 0; jj < 4; jj++) { EDGE_FMA(B, j + jj) }
                j += 4;
            }
            for (; j < take; j++) { EDGE_FMA(B, j) }
        }
    }
    float di = dinv[node];
    float agg = fmaf(di, acc, B[(size_t)node * 16 + ln] * di * di);
    float h2a = sb2[ln], h2b = sb2[ln + 16];
    #pragma unroll
    for (int k = 0; k < 16; k++) {
        float ak = __shfl(agg, k, 16);
        h2a += ak * sW[k * 32 + ln];
        h2b += ak * sW[k * 32 + ln + 16];
    }
    h2a = elu_f(h2a); h2b = elu_f(h2b);
    float m0 = sLb[ln], m1 = sLb[ln + 16];
    #pragma unroll
    for (int k = 0; k < 16; k++) {
        float a0 = __shfl(h2a, k, 16);
        float a1 = __shfl(h2b, k, 16);
        m0 += a0 * sL[k * 32 + ln]        + a1 * sL[(k + 16) * 32 + ln];
        m1 += a0 * sL[k * 32 + ln + 16]   + a1 * sL[(k + 16) * 32 + ln + 16];
    }
    float* mr = M + (size_t)node * 32;
    mr[ln] = m0; mr[ln + 16] = m1;
}

// ---------------- bipartite gather fused with MLP head ----------------

__global__ void k_bi_mlp(const int* __restrict__ srcs, const int* __restrict__ rs,
                         const float* __restrict__ M, const float* __restrict__ mw,
                         const float* __restrict__ mb, float* __restrict__ out, int N) {
    __shared__ float sW[32 * 10];
    __shared__ float sb[10];
    for (int t = threadIdx.x; t < 320; t += blockDim.x) sW[t] = mw[t];
    if (threadIdx.x < 10) sb[threadIdx.x] = mb[threadIdx.x];
    __syncthreads();
    int t = blockIdx.x * blockDim.x + threadIdx.x;
    int node = t >> 5, ln = t & 31;
    if (node >= N) return;
    int beg = rs[node], end = rs[node + 1];
    float acc = 0.0f;
    for (int k = beg; k < end; k += 32) {
        int take = end - k; if (take > 32) take = 32;
        int ms = srcs[k + (ln < take ? ln : take - 1)];
        if (take == 32) {
            #pragma unroll
            for (int j = 0; j < 32; j++)
                acc += M[(size_t)__shfl(ms, j, 32) * 32 + ln];
        } else {
            int j = 0;
            if (take >= 16) {
                #pragma unroll
                for (int jj = 0; jj < 16; jj++)
                    acc += M[(size_t)__shfl(ms, jj, 32) * 32 + ln];
                j = 16;
            }
            if (take - j >= 8) {
                #pragma unroll
                for (int jj = 0; jj < 8; jj++)
                    acc += M[(size_t)__shfl(ms, j + jj, 32) * 32 + ln];
                j += 8;
            }
            if (take - j >= 4) {
                #pragma unroll
                for (int jj = 0; jj < 4; jj++)
                    acc += M[(size_t)__shfl(ms, j + jj, 32) * 32 + ln];
                j += 4;
            }
            for (; j < take; j++)
                acc += M[(size_t)__shfl(ms, j, 32) * 32 + ln];
        }
    }
    float e = elu_f(acc);
    int lw = ln < 10 ? ln : 0;
    float o = ln < 10 ? sb[ln] : 0.0f;
    #pragma unroll
    for (int k = 0; k < 32; k++) {
        float ak = __shfl(e, k, 32);
        o += ak * sW[k * 10 + lw];
    }
    if (ln < 10) out[(size_t)node * 10 + ln] = o;
}

// ---------------- launch ----------------

extern "C" void kernel_launch(void* const* d_in, const int* in_sizes, int n_in,
                              void* d_out, int out_size, void* d_ws, size_t ws_size,
                              hipStream_t stream) {
    const float* x_ho   = (const float*)d_in[0];
    const int*   ho_src = (const int*)d_in[2];
    const int*   ho_dst = (const int*)d_in[3];
    const float* ho_w   = (const float*)d_in[4];
    const int*   bi_src = (const int*)d_in[8];
    const int*   bi_dst = (const int*)d_in[9];
    const float* W220   = (const float*)d_in[12];
    const float* b220   = (const float*)d_in[13];
    const float* W221   = (const float*)d_in[14];
    const float* b221   = (const float*)d_in[15];
    const float* lin1_w = (const float*)d_in[20];
    const float* lin1_b = (const float*)d_in[21];
    const float* mlp_w  = (const float*)d_in[24];
    const float* mlp_b  = (const float*)d_in[25];

    const int NHO = in_sizes[0] / 60;
    const int EHO = in_sizes[2];
    const int EBI = in_sizes[8];
    const int NFO = out_size / 10;
    float* out = (float*)d_out;

    const int NB = (NHO + BKSZ - 1) / BKSZ;              // 782
    const int nChunks = (EHO + CH - 1) / CH;             // 245
    const int NC = NB * nChunks;                         // counts cells
    const int biB = 2048;
    const int xwB = (NHO + 63) / 64;

    // ---- workspace layout (4-byte words); int2 arrays first for 8B alignment ----
    size_t off = 0;
    float* ws = (float*)d_ws;
    int2*  pairs = (int2*)(ws + off); off += (size_t)2 * EHO;
    size_t uWords = (size_t)2 * EHO;                     // U = max(eS, B)
    if ((size_t)16 * NHO > uWords) uWords = (size_t)16 * NHO;
    int2*  eS = (int2*)(ws + off);
    float* B  = (float*)(ws + off); off += uWords;       // eS dead before B is written
    float* A  = ws + off; off += (size_t)32 * NHO;       // xw1 (16 used); M overlays
    float* M  = A;
    float* dinv  = ws + off; off += NHO;
    int*   rs_ho = (int*)(ws + off); off += NHO + 1;
    int*   counts  = (int*)(ws + off); off += NC;
    int*   countsS = (int*)(ws + off); off += NC + 1;
    int*   cntBI = (int*)(ws + off); off += NFO;
    int*   rs_bi = (int*)(ws + off); off += NFO + 1;
    int*   srcbi = (int*)(ws + off); off += EBI;
    unsigned short* rankBI = (unsigned short*)(ws + off); off += (EBI + 1) / 2;
    int*   sums1 = (int*)(ws + off); off += SCAN_BLOCK;
    int*   sums2 = (int*)(ws + off); off += SCAN_BLOCK;

    const int BLK = 256;
    const int nb1 = (NC + SCAN_BLOCK - 1) / SCAN_BLOCK;
    const int nb2 = (NFO + SCAN_BLOCK - 1) / SCAN_BLOCK;

    // zero only the BI atomic counters
    hipMemsetAsync(cntBI, 0, (size_t)NFO * 4, stream);

    // pass A: HO bucket hist (LDS) || BI atomics || x @ W220
    k_passA<<<nChunks + biB + xwB, BLK, 0, stream>>>(
        ho_dst, counts, nChunks, EHO, NB,
        bi_dst, cntBI, rankBI, EBI, biB,
        x_ho, W220, A, NHO);

    // scans: counts matrix (bucket-major) and BI counters
    k_scan2<<<nb1 + nb2, SCAN_BLOCK, 0, stream>>>(
        counts, countsS, NC, nb1, cntBI, rs_bi, NFO, sums1, sums2);
    k_scan_sums2<<<2, SCAN_BLOCK, 0, stream>>>(sums1, nb1, sums2, nb2);
    k_scan_add2<<<nb1 + nb2, SCAN_BLOCK, 0, stream>>>(
        countsS, sums1, NC, EHO, nb1, rs_bi, sums2, NFO, EBI);

    // pass C: bucket-ordered scatter + BI fill
    k_passC<<<nChunks + 2048, BLK, 0, stream>>>(
        ho_src, ho_dst, ho_w, countsS, nChunks, NB, EHO, eS,
        bi_src, bi_dst, rankBI, rs_bi, srcbi, EBI);

    // pass D: per-bucket CSR finalize (rs_ho, dinv, pairs)
    k_passD<<<NB, SCAN_BLOCK, 0, stream>>>(
        eS, countsS, nChunks, NB, EHO, NHO, pairs, rs_ho, dinv);

    // pass E: pairs.w *= dinv[src]
    {
        long long b = ((long long)EHO + BLK - 1) / BLK;
        k_passE<<<(int)(b > 4096 ? 4096 : b), BLK, 0, stream>>>(pairs, dinv, EHO);
    }

    // B = elu(gcn1)
    {
        long long t = (long long)NHO * 16;
        k_gather1<<<(int)((t + BLK - 1) / BLK), BLK, 0, stream>>>(
            pairs, rs_ho, dinv, A, b220, B, NHO);
    }
    // M = (elu(gcn2)) @ lin1 + lin1_b
    {
        long long t = (long long)NHO * 16;
        k_gather2<<<(int)((t + BLK - 1) / BLK), BLK, 0, stream>>>(
            pairs, rs_ho, dinv, B, W221, b221, lin1_w, lin1_b, M, NHO);
    }
    // out = elu(bipartite sum of M) @ mlp_w + mlp_b
    {
        long long t = (long long)NFO * 32;
        k_bi_mlp<<<(int)((t + BLK - 1) / BLK), BLK, 0, stream>>>(
            srcbi, rs_bi, M, mlp_w, mlp_b, out, NFO);
    }
}